// Round 8
// baseline (1007.130 us; speedup 1.0000x reference)
//
#include <hip/hip_runtime.h>
#include <math.h>

#define TPB 256
#define MAXR 200
#define MAXEP 4608   // max padded CSR slots: E/G + R*7 <= 3200+1400=4600

typedef float f32x4 __attribute__((ext_vector_type(4)));
typedef __bf16 bfv8 __attribute__((ext_vector_type(8)));

union U8 { uint4 q; unsigned short us[8]; __bf16 b[8]; bfv8 v; };

__device__ __forceinline__ unsigned short f2bfu(float f) {
  union { __bf16 h; unsigned short u; } x;
  x.h = (__bf16)f;
  return x.u;
}
__device__ __forceinline__ float bfu2f(unsigned short u) {
  return __uint_as_float((unsigned)u << 16);
}

__device__ __forceinline__ float mish_f(float x) {
  float sp = fmaxf(x, 0.f) + log1pf(expf(-fabsf(x)));
  return x * tanhf(sp);
}

// ---------------------------------------------------------------------------
// gemm2 (R6-verified): C = alpha*(A @ Bt^T) + bias [, mish].
// A (N,lda) bf16/fp32; bf16 lda mult-8 -> unconditional uint4 frag loads.
// Bt contiguous bf16 (M,Kpad) panel, zero-padded in k. Kpad%16==8.
// ---------------------------------------------------------------------------
__device__ __forceinline__ U8 loadA_f32(const float* Af, int kb, int K, bool rowok) {
  U8 u;
  if (rowok && kb + 8 <= K) {
    float4 f0 = *(const float4*)(Af + kb);
    float4 f1 = *(const float4*)(Af + kb + 4);
    u.b[0]=(__bf16)f0.x; u.b[1]=(__bf16)f0.y; u.b[2]=(__bf16)f0.z; u.b[3]=(__bf16)f0.w;
    u.b[4]=(__bf16)f1.x; u.b[5]=(__bf16)f1.y; u.b[6]=(__bf16)f1.z; u.b[7]=(__bf16)f1.w;
  } else {
#pragma unroll
    for (int j = 0; j < 8; ++j) {
      float f = (rowok && kb + j < K) ? Af[kb + j] : 0.f;
      u.b[j] = (__bf16)f;
    }
  }
  return u;
}

template<bool ABF16, bool CBF16, bool MISH, int NJ, int KPMAX>
__global__ __launch_bounds__(256) void gemm2(
    const void* __restrict__ Av, const unsigned short* __restrict__ Bt,
    const float* __restrict__ bias, void* __restrict__ Cv,
    int N, int M, int K, int lda, int ldc,
    long sA, long sB, long sC, float alpha, int Kpad)
{
  constexpr int BM = NJ * 16;
  __shared__ unsigned short Bs[BM * KPMAX];

  const int tid = threadIdx.x;
  const int col0 = blockIdx.x * BM, row0 = blockIdx.y * 64;

  // ---- stage B panel: contiguous uint4 copy, 4-deep ----
  {
    const unsigned short* Bp = Bt + (long)blockIdx.z * sB + (long)col0 * Kpad;
    int rows = M - col0; if (rows > BM) rows = BM;
    const int total = rows * Kpad;
    for (int i = tid * 8; i < total; i += TPB * 32) {
      uint4 a0, a1, a2, a3;
      bool b1 = i + TPB * 8  < total;
      bool b2 = i + TPB * 16 < total;
      bool b3 = i + TPB * 24 < total;
      a0 = *(const uint4*)&Bp[i];
      if (b1) a1 = *(const uint4*)&Bp[i + TPB * 8];
      if (b2) a2 = *(const uint4*)&Bp[i + TPB * 16];
      if (b3) a3 = *(const uint4*)&Bp[i + TPB * 24];
      *(uint4*)&Bs[i] = a0;
      if (b1) *(uint4*)&Bs[i + TPB * 8]  = a1;
      if (b2) *(uint4*)&Bs[i + TPB * 16] = a2;
      if (b3) *(uint4*)&Bs[i + TPB * 24] = a3;
    }
  }

  const int lane = tid & 63, w = tid >> 6;
  const int mrow = lane & 15, kg = lane >> 4;
  const int arow = row0 + w * 16 + mrow;
  const bool rowok = arow < N;

  const unsigned short* Ah = nullptr;
  const float* Af = nullptr;
  if (ABF16) Ah = (const unsigned short*)Av + (long)blockIdx.z * sA + (long)arow * lda;
  else       Af = (const float*)Av + (long)blockIdx.z * sA + (long)arow * lda;

  U8 ua;
  if (ABF16) ua.q = *(const uint4*)(Ah + kg * 8);
  else       ua   = loadA_f32(Af, kg * 8, K, rowok);

  __syncthreads();

  f32x4 acc[NJ];
#pragma unroll
  for (int j = 0; j < NJ; ++j) acc[j] = (f32x4)0.f;

  for (int k0 = 0; k0 < K; k0 += 32) {
    U8 un;
    bool more = (k0 + 32) < K;
    if (more) {
      if (ABF16) un.q = *(const uint4*)(Ah + k0 + 32 + kg * 8);
      else       un   = loadA_f32(Af, k0 + 32 + kg * 8, K, rowok);
    }
    const int kb = k0 + kg * 8;
#pragma unroll
    for (int j = 0; j < NJ; ++j) {
      U8 ub;
      ub.q = *(const uint4*)&Bs[(j * 16 + mrow) * Kpad + kb];
      acc[j] = __builtin_amdgcn_mfma_f32_16x16x32_bf16(ua.v, ub.v, acc[j], 0, 0, 0);
    }
    if (more) ua = un;
  }

  long cbase = (long)blockIdx.z * sC;
#pragma unroll
  for (int j = 0; j < NJ; ++j) {
    int gc = col0 + j * 16 + mrow;
    if (gc >= M) continue;
    float bb = bias ? bias[gc] : 0.f;
#pragma unroll
    for (int r = 0; r < 4; ++r) {
      int gr = row0 + w * 16 + kg * 4 + r;
      if (gr >= N) continue;
      float v = acc[j][r] * alpha + bb;
      if (MISH) v = mish_f(v);
      if (CBF16) ((unsigned short*)Cv)[cbase + (long)gr * ldc + gc] = f2bfu(v);
      else       ((float*)Cv)[cbase + (long)gr * ldc + gc] = v;
    }
  }
}

static inline int kpad_of(int K) { return ((K + 31) / 32) * 32 + 8; }

// ---------------------------------------------------------------------------
// prep: weights -> pre-transposed bf16 (M,Kpad) panels; bias concat.
// ---------------------------------------------------------------------------
struct PrepSeg { const float* src; void* dst; int K, M, Kpad, kind; };
struct PrepArgs { PrepSeg s[19]; };

__global__ __launch_bounds__(256) void prep_weights(PrepArgs a) {
  PrepSeg sg = a.s[blockIdx.x];
  if (sg.kind == 0) {
    unsigned short* d = (unsigned short*)sg.dst;
    int tot = sg.M * sg.Kpad;
    for (int i = threadIdx.x; i < tot; i += TPB) {
      int m = i / sg.Kpad, k = i - m * sg.Kpad;
      float f = (k < sg.K) ? sg.src[(long)k * sg.M + m] : 0.f;
      d[i] = f2bfu(f);
    }
  } else {
    float* d = (float*)sg.dst;
    for (int i = threadIdx.x; i < sg.K; i += TPB) d[i] = sg.src[i];
  }
}

// x (N,C) fp32 -> xb (N,S) bf16 zero-padded. grid = N/8 blocks.
__global__ __launch_bounds__(256) void xcast(const float* __restrict__ x,
                                             unsigned short* __restrict__ xb,
                                             int C, int S)
{
  long r0 = (long)blockIdx.x * 8;
  for (int i = threadIdx.x; i < 8 * S; i += TPB) {
    int rr = i / S, c = i - rr * S;
    long r = r0 + rr;
    xb[r * S + c] = f2bfu(c < C ? x[r * C + c] : 0.f);
  }
}

// per-graph: Kt (R,72) contiguous bf16 slice of K; Vt (64,Rpad) transposed V.
__global__ __launch_bounds__(256) void ktvt_kernel(
    const unsigned short* __restrict__ QKV, unsigned short* __restrict__ Kt,
    unsigned short* __restrict__ Vt, int R, int Rpad)
{
  int g = blockIdx.x;
  const unsigned short* q = QKV + (long)g * R * 192;
  unsigned short* kt = Kt + (long)g * R * 72;
  unsigned short* vt = Vt + (long)g * 64 * Rpad;
  int c = threadIdx.x & 63, w = threadIdx.x >> 6;
  for (int r = w; r < R; r += 4) {
    kt[r * 72 + c] = q[(long)r * 192 + 64 + c];
    vt[c * Rpad + r] = q[(long)r * 192 + 128 + c];
  }
  int pad = Rpad - R;
  for (int i = threadIdx.x; i < 64 * pad; i += TPB) {
    int cc = i / pad, k = i - cc * pad;
    vt[cc * Rpad + R + k] = 0;
  }
}

// ---------------------------------------------------------------------------
// adj_build: dense normalized adjacency per graph, bf16 (R x Rpad), zero-pad,
// self-loop folded in.  A[d][s] = dinv[d]*dinv[s]*cnt(s->d) + (s==d)*dinv^2.
// CSR counting-sort (R7-verified pattern) -> wave-private dense rowbuf.
// ---------------------------------------------------------------------------
__global__ __launch_bounds__(256) void adj_build(
    const int* __restrict__ src, const int* __restrict__ dst,
    unsigned short* __restrict__ Adj, int R, int Rpad, int EPG)
{
  __shared__ float dinv_s[256];
  __shared__ unsigned short ssrc[MAXEP];
  __shared__ int cnt[256];
  __shared__ int scan[256];
  __shared__ int offx[257];
  __shared__ int cur[256];
  __shared__ float rowbuf[4][256];

  int g = blockIdx.x, tid = threadIdx.x;
  long ebase = (long)g * EPG;
  int gR = g * R;

  cnt[tid] = 0;
  __syncthreads();
  for (int e = tid; e < EPG; e += TPB)
    atomicAdd(&cnt[dst[ebase + e] - gR], 1);
  __syncthreads();

  int x = cnt[tid];
  int pc = (x + 7) & ~7;
  scan[tid] = pc;
  __syncthreads();
#pragma unroll
  for (int s = 1; s < 256; s <<= 1) {
    int t = (tid >= s) ? scan[tid - s] : 0;
    __syncthreads();
    scan[tid] += t;
    __syncthreads();
  }
  if (tid == 0) offx[0] = 0;
  offx[tid + 1] = scan[tid];
  cur[tid] = scan[tid] - pc;
  dinv_s[tid] = rsqrtf((float)x + 1.f);
  {
    unsigned dummy2 = 0xFFFFFFFFu;   // 0xFFFF > R -> guarded out
    for (int i = tid; i < MAXEP / 2; i += TPB) ((unsigned*)ssrc)[i] = dummy2;
  }
  __syncthreads();

  for (int e = tid; e < EPG; e += TPB) {
    int d = dst[ebase + e] - gR;
    int s = src[ebase + e] - gR;
    int pos = atomicAdd(&cur[d], 1);
    ssrc[pos] = (unsigned short)s;
  }
  __syncthreads();

  int lane = tid & 63, w = tid >> 6;
  float* rb = rowbuf[w];
  for (int d = w; d < R; d += 4) {
    // zero row buffer (covers Rpad <= 256)
#pragma unroll
    for (int i = 0; i < 4; ++i) rb[lane + i * 64] = 0.f;
    int i0 = offx[d], i1 = offx[d + 1];
    for (int i = i0 + lane; i < i1; i += 64) {
      int s = ssrc[i];
      if (s < R) atomicAdd(&rb[s], dinv_s[s]);   // duplicates accumulate
    }
    float dd = dinv_s[d];
    // write row * dinv[d], self-loop folded at read; 4 shorts per lane
    int c0 = lane * 4;
    if (c0 < Rpad) {
      ushort4 o;
      float v0 = rb[c0]     + (c0     == d ? dd : 0.f);
      float v1 = rb[c0 + 1] + (c0 + 1 == d ? dd : 0.f);
      float v2 = rb[c0 + 2] + (c0 + 2 == d ? dd : 0.f);
      float v3 = rb[c0 + 3] + (c0 + 3 == d ? dd : 0.f);
      o.x = f2bfu(v0 * dd); o.y = f2bfu(v1 * dd);
      o.z = f2bfu(v2 * dd); o.w = f2bfu(v3 * dd);
      *(ushort4*)&Adj[((long)gR + d) * Rpad + c0] = o;
    }
  }
}

// transp64: per-graph (R x 64) bf16 -> (64 x Rpad) bf16, zero-padded cols>=R.
// LDS-tile; coalesced global reads and 16B coalesced writes.
__global__ __launch_bounds__(256) void transp64(
    const unsigned short* __restrict__ X, unsigned short* __restrict__ XT,
    int R, int Rpad)
{
  __shared__ unsigned short tile[64][72];
  int g = blockIdx.x, tid = threadIdx.x;
  const unsigned short* xg = X + (long)g * R * 64;
  unsigned short* xt = XT + (long)g * 64 * Rpad;
  for (int r0 = 0; r0 < Rpad; r0 += 64) {
    __syncthreads();
    for (int i = tid; i < 64 * 64; i += TPB) {
      int rr = i >> 6, cc = i & 63;
      int r = r0 + rr;
      tile[cc][rr] = (r < R) ? xg[(long)r * 64 + cc] : (unsigned short)0;
    }
    __syncthreads();
    int c = tid >> 2, j0 = (tid & 3) * 16;
    int lim = Rpad - r0; if (lim > 64) lim = 64;
    for (int jj = j0; jj < j0 + 16 && jj < lim; jj += 8) {
      uint4 q = *(const uint4*)&tile[c][jj];   // (c*72+jj)*2 is 16B-aligned
      *(uint4*)&xt[(long)c * Rpad + r0 + jj] = q;
    }
  }
}

// wave-per-row softmax in place on bf16; row length R <= 256
__global__ __launch_bounds__(256) void softmax_bf16(unsigned short* __restrict__ S,
                                                    int R, long rows)
{
  long wid = (long)blockIdx.x * 4 + (threadIdx.x >> 6);
  if (wid >= rows) return;
  int lane = threadIdx.x & 63;
  unsigned short* row = S + wid * R;
  float v[4];
  float mx = -1e30f;
#pragma unroll
  for (int t = 0; t < 4; ++t) {
    int j = lane + t * 64;
    v[t] = (j < R) ? bfu2f(row[j]) : -1e30f;
    mx = fmaxf(mx, v[t]);
  }
#pragma unroll
  for (int o = 32; o; o >>= 1) mx = fmaxf(mx, __shfl_xor(mx, o));
  float s = 0.f;
#pragma unroll
  for (int t = 0; t < 4; ++t) {
    int j = lane + t * 64;
    if (j < R) { v[t] = expf(v[t] - mx); s += v[t]; }
  }
#pragma unroll
  for (int o = 32; o; o >>= 1) s += __shfl_xor(s, o);
  float inv = 1.f / s;
#pragma unroll
  for (int t = 0; t < 4; ++t) {
    int j = lane + t * 64;
    if (j < R) row[j] = f2bfu(v[t] * inv);
  }
}

// out[idx] = inv * sum_g S[g*RR + idx]; 8-way unrolled
__global__ void meang_bf16(const unsigned short* __restrict__ S, float* __restrict__ out,
                           int RR, int G, float inv)
{
  int idx = blockIdx.x * TPB + threadIdx.x;
  if (idx >= RR) return;
  const unsigned short* p = S + idx;
  float s = 0.f;
  for (int g = 0; g + 8 <= G; g += 8) {
    s += bfu2f(p[(long)g * RR])       + bfu2f(p[(long)(g + 1) * RR]) +
         bfu2f(p[(long)(g + 2) * RR]) + bfu2f(p[(long)(g + 3) * RR]) +
         bfu2f(p[(long)(g + 4) * RR]) + bfu2f(p[(long)(g + 5) * RR]) +
         bfu2f(p[(long)(g + 6) * RR]) + bfu2f(p[(long)(g + 7) * RR]);
  }
  out[idx] = s * inv;
}

// per-graph mean over R rows (bf16 in). grid=G, 256 threads (4-wave parallel).
__global__ __launch_bounds__(256) void pool_mean_bf16(const unsigned short* __restrict__ X,
                                                      float* __restrict__ out, int R)
{
  __shared__ float part[4][64];
  int g = blockIdx.x, lane = threadIdx.x & 63, w = threadIdx.x >> 6;
  float s = 0.f;
  for (int r = w; r < R; r += 4)
    s += bfu2f(X[((long)g * R + r) * 64 + lane]);
  part[w][lane] = s;
  __syncthreads();
  if (w == 0)
    out[g * 64 + lane] = (part[0][lane] + part[1][lane] + part[2][lane] + part[3][lane]) * (1.f / R);
}

// per-graph mean over V gathered rows (bf16 in). grid=G, 64 threads.
__global__ __launch_bounds__(64) void sub_mean_kernel(const unsigned short* __restrict__ X,
                                                      const int* __restrict__ sub,
                                                      float* __restrict__ out, int V)
{
  int g = blockIdx.x, lane = threadIdx.x;
  float s = 0.f;
  for (int v = 0; v + 4 <= V; v += 4) {
    int i0 = sub[g * V + v],     i1 = sub[g * V + v + 1];
    int i2 = sub[g * V + v + 2], i3 = sub[g * V + v + 3];
    s += bfu2f(X[(long)i0 * 64 + lane]) + bfu2f(X[(long)i1 * 64 + lane]) +
         bfu2f(X[(long)i2 * 64 + lane]) + bfu2f(X[(long)i3 * 64 + lane]);
  }
  out[g * 64 + lane] = s * (1.f / V);
}

__global__ __launch_bounds__(64) void norm_rows_kernel(const float* __restrict__ X,
                                                       float* __restrict__ Y)
{
  int g = blockIdx.x, lane = threadIdx.x;
  float x = X[g * 64 + lane];
  float ss = x * x;
#pragma unroll
  for (int o = 32; o; o >>= 1) ss += __shfl_xor(ss, o);
  float n = fmaxf(sqrtf(ss), 1e-12f);
  Y[g * 64 + lane] = x / n;
}

__global__ __launch_bounds__(256) void closs_kernel(const float* __restrict__ An,
                                                    const float* __restrict__ Bn,
                                                    float* __restrict__ loss, int G,
                                                    float invTemp, float coef)
{
  int i = blockIdx.x;
  __shared__ float arow[64];
  __shared__ float logits[512];
  __shared__ float red[256];
  int t = threadIdx.x;
  if (t < 64) arow[t] = An[i * 64 + t];
  __syncthreads();
  for (int j = t; j < G; j += 256) {
    const float* bp = Bn + (long)j * 64;
    float d = 0.f;
#pragma unroll
    for (int k = 0; k < 64; ++k) d = fmaf(arow[k], bp[k], d);
    logits[j] = d * invTemp;
  }
  __syncthreads();
  float mx = -1e30f;
  for (int j = t; j < G; j += 256) mx = fmaxf(mx, logits[j]);
  red[t] = mx; __syncthreads();
  for (int o = 128; o; o >>= 1) { if (t < o) red[t] = fmaxf(red[t], red[t + o]); __syncthreads(); }
  mx = red[0]; __syncthreads();
  float s = 0.f;
  for (int j = t; j < G; j += 256) s += expf(logits[j] - mx);
  red[t] = s; __syncthreads();
  for (int o = 128; o; o >>= 1) { if (t < o) red[t] += red[t + o]; __syncthreads(); }
  if (t == 0) {
    float lse = mx + logf(red[0]);
    atomicAdd(loss, coef * (lse - logits[i]));
  }
}

__global__ __launch_bounds__(128) void head_kernel(
    const float* __restrict__ s1, const float* __restrict__ z1,
    const float* __restrict__ s2, const float* __restrict__ z2,
    const float* __restrict__ W1, const float* __restrict__ b1,
    const float* __restrict__ W2, const float* __restrict__ b2,
    float* __restrict__ out)
{
  int g = blockIdx.x, t = threadIdx.x;
  __shared__ float feat[256];
  __shared__ float hid[128];
  if (t < 64) {
    feat[t]       = s1[g * 64 + t];
    feat[64 + t]  = z1[g * 64 + t];
    feat[128 + t] = s2[g * 64 + t];
    feat[192 + t] = z2[g * 64 + t];
  }
  __syncthreads();
  float acc = b1[t];
  for (int k = 0; k < 256; ++k) acc = fmaf(feat[k], W1[k * 128 + t], acc);
  hid[t] = mish_f(acc);
  __syncthreads();
  if (t < 2) {
    float a2 = b2[t];
#pragma unroll
    for (int k = 0; k < 128; ++k) a2 = fmaf(hid[k], W2[k * 2 + t], a2);
    out[g * 2 + t] = a2;
  }
}

#define LAUNCH_GEMM(ABF,CBF,MISH,NJ,KP, A,B,BI,C, N,M,K,LDA,LDC,SA,SB,SC,BAT,AL,KPAD) \
  { dim3 g_(((M)+(NJ)*16-1)/((NJ)*16), ((N)+63)/64, (BAT)); \
    gemm2<ABF,CBF,MISH,NJ,KP><<<g_,256,0,stream>>>((A),(B),(BI),(C),(N),(M),(K),(LDA),(LDC),(SA),(SB),(SC),(AL),(KPAD)); }

extern "C" void kernel_launch(void* const* d_in, const int* in_sizes, int n_in,
                              void* d_out, int out_size, void* d_ws, size_t ws_size,
                              hipStream_t stream)
{
  const float* x1     = (const float*)d_in[0];
  const float* x2     = (const float*)d_in[1];
  const float* fcl_W  = (const float*)d_in[2];  const float* fcl_b  = (const float*)d_in[3];
  const float* fcr_W  = (const float*)d_in[4];  const float* fcr_b  = (const float*)d_in[5];
  const float* fcl1_W = (const float*)d_in[6];  const float* fcl1_b = (const float*)d_in[7];
  const float* fcr1_W = (const float*)d_in[8];  const float* fcr1_b = (const float*)d_in[9];
  const float* a1qW = (const float*)d_in[10]; const float* a1qb = (const float*)d_in[11];
  const float* a1kW = (const float*)d_in[12]; const float* a1kb = (const float*)d_in[13];
  const float* a1vW = (const float*)d_in[14]; const float* a1vb = (const float*)d_in[15];
  const float* a2qW = (const float*)d_in[16]; const float* a2qb = (const float*)d_in[17];
  const float* a2kW = (const float*)d_in[18]; const float* a2kb = (const float*)d_in[19];
  const float* a2vW = (const float*)d_in[20]; const float* a2vb = (const float*)d_in[21];
  const float* convW  = (const float*)d_in[22]; const float* convb  = (const float*)d_in[23];
  const float* conv1W = (const float*)d_in[24]; const float* conv1b = (const float*)d_in[25];
  const float* mlpW   = (const float*)d_in[26]; const float* mlpb   = (const float*)d_in[27];
  const float* fc1aW  = (const float*)d_in[28]; const float* fc1ab  = (const float*)d_in[29];
  const float* fc1bW  = (const float*)d_in[30]; const float* fc1bb  = (const float*)d_in[31];
  const int* ei1  = (const int*)d_in[32];
  const int* ei2  = (const int*)d_in[33];
  const int* sub1 = (const int*)d_in[36];
  const int* sub2 = (const int*)d_in[37];

  const int R1 = in_sizes[6] / 128;       // 200
  const int R2 = in_sizes[8] / 128;       // 160
  const int N1 = in_sizes[34];            // 102400
  const int N2 = in_sizes[35];            // 81920
  const int G  = N1 / R1;                 // 512
  const int E1 = in_sizes[32] / 2, E2 = in_sizes[33] / 2;
  const int EPG1 = E1 / G, EPG2 = E2 / G;
  const int V = in_sizes[36] / G;

  const int XS = 232;
  const int Kp1  = kpad_of(R1);           // 232
  const int Kp2  = kpad_of(R2);           // 168
  const int Kp1f = kpad_of(R1 + 3);       // 232
  const int Kp2f = kpad_of(R2 + 3);       // 200
  const int Rpad1 = Kp1, Rpad2 = Kp2;

  // ---------------- workspace layout ----------------
  char* wp = (char*)d_ws;
  auto alloc = [&](size_t bytes) -> char* {
    char* p = wp; wp += (bytes + 255) & ~(size_t)255; return p;
  };
  unsigned short* x1b = (unsigned short*)alloc((size_t)N1 * XS * 2);
  unsigned short* x2b = (unsigned short*)alloc((size_t)N2 * XS * 2);
  size_t raSh = (size_t)G * R1 * R1;
  if ((size_t)N1 * 128 > raSh) raSh = (size_t)N1 * 128;
  unsigned short* RA = (unsigned short*)alloc(raSh * 2);
  unsigned short* RB = (unsigned short*)alloc((size_t)N1 * 192 * 2);
  unsigned short* Kt = (unsigned short*)alloc((size_t)G * R1 * 72 * 2);
  unsigned short* Vt = (unsigned short*)alloc((size_t)G * 64 * Rpad1 * 2);  // also hW^T
  unsigned short* W5 = (unsigned short*)alloc((size_t)N1 * 64 * 2);         // PV out bf16
  unsigned short* fcl1t  = (unsigned short*)alloc((size_t)128 * Kp1 * 2);
  unsigned short* fcr1t  = (unsigned short*)alloc((size_t)128 * Kp2 * 2);
  unsigned short* fclt   = (unsigned short*)alloc((size_t)128 * Kp1f * 2);
  unsigned short* fcrt   = (unsigned short*)alloc((size_t)128 * Kp2f * 2);
  unsigned short* Wc1t   = (unsigned short*)alloc((size_t)192 * 136 * 2);
  unsigned short* Wc2t   = (unsigned short*)alloc((size_t)192 * 136 * 2);
  unsigned short* convt  = (unsigned short*)alloc((size_t)64 * 136 * 2);
  unsigned short* conv1t = (unsigned short*)alloc((size_t)64 * 72 * 2);
  unsigned short* mlpt   = (unsigned short*)alloc((size_t)64 * 72 * 2);
  float* bc1 = (float*)alloc(192 * 4);
  float* bc2 = (float*)alloc(192 * 4);
  float* Pz1 = (float*)alloc((size_t)G * 64 * 4);
  float* Pz2 = (float*)alloc((size_t)G * 64 * 4);
  float* Ps1 = (float*)alloc((size_t)G * 64 * 4);
  float* Ps2 = (float*)alloc((size_t)G * 64 * 4);
  float* Mt  = (float*)alloc((size_t)G * 64 * 4);
  float* n_s1 = (float*)alloc((size_t)G * 64 * 4);
  float* n_z2 = (float*)alloc((size_t)G * 64 * 4);
  float* n_z1 = (float*)alloc((size_t)G * 64 * 4);
  float* n_s2 = (float*)alloc((size_t)G * 64 * 4);
  (void)alloc(4096);

  // Adj reuses x1b/x2b (dead after their fcl/fcr projections; exact-size fit:
  // N1*XS == G*R1*Rpad1, and G*R2*Rpad2 < N2*XS).
  unsigned short* Adj1 = x1b;
  unsigned short* Adj2 = x2b;

  float* loss = (float*)d_out;
  float* outp = loss + 1;
  float* aw1  = outp + (size_t)G * 2;
  float* aw2  = aw1 + (size_t)R1 * R1;

  hipMemsetAsync(d_out, 0, sizeof(float), stream);

  // ---------------- prep ----------------
  PrepArgs pa;
  int seg = 0;
  auto addp = [&](const float* s, unsigned short* d, int K, int M, int Kp) {
    pa.s[seg].src = s; pa.s[seg].dst = d; pa.s[seg].K = K; pa.s[seg].M = M;
    pa.s[seg].Kpad = Kp; pa.s[seg].kind = 0; seg++;
  };
  auto addb = [&](const float* s, float* d, int n) {
    pa.s[seg].src = s; pa.s[seg].dst = d; pa.s[seg].K = n; pa.s[seg].M = 0;
    pa.s[seg].Kpad = 0; pa.s[seg].kind = 1; seg++;
  };
  addp(fcl1_W, fcl1t, R1, 128, Kp1);
  addp(fcr1_W, fcr1t, R2, 128, Kp2);
  addp(fcl_W,  fclt,  R1 + 3, 128, Kp1f);
  addp(fcr_W,  fcrt,  R2 + 3, 128, Kp2f);
  addp(a1qW, Wc1t,             128, 64, 136);
  addp(a1kW, Wc1t + 64 * 136,  128, 64, 136);
  addp(a1vW, Wc1t + 128 * 136, 128, 64, 136);
  addp(a2qW, Wc2t,             128, 64, 136);
  addp(a2kW, Wc2t + 64 * 136,  128, 64, 136);
  addp(a2vW, Wc2t + 128 * 136, 128, 64, 136);
  addp(convW,  convt,  128, 64, 136);
  addp(conv1W, conv1t, 64, 64, 72);
  addp(mlpW,   mlpt,   64, 64, 72);
  addb(a1qb, bc1, 64); addb(a1kb, bc1 + 64, 64); addb(a1vb, bc1 + 128, 64);
  addb(a2qb, bc2, 64); addb(a2kb, bc2 + 64, 64); addb(a2vb, bc2 + 128, 64);
  prep_weights<<<seg, 256, 0, stream>>>(pa);

  xcast<<<N1 / 8, 256, 0, stream>>>(x1, x1b, R1 + 3, XS);
  xcast<<<N2 / 8, 256, 0, stream>>>(x2, x2b, R2 + 3, XS);

  // ======== attention branch, side 1 ========
  LAUNCH_GEMM(true, true, false, 8, 232, x1b, fcl1t, fcl1_b, RA,
              N1, 128, R1, XS, 128, 0, 0, 0, 1, 1.f, Kp1);
  LAUNCH_GEMM(true, true, false, 12, 136, RA, Wc1t, bc1, RB,
              N1, 192, 128, 128, 192, 0, 0, 0, 1, 1.f, 136);
  ktvt_kernel<<<G, 256, 0, stream>>>(RB, Kt, Vt, R1, Rpad1);
  LAUNCH_GEMM(true, true, false, 8, 72, RB, Kt, nullptr, RA,
              R1, R1, 64, 192, R1, (long)R1 * 192, (long)R1 * 72, (long)R1 * R1,
              G, 0.125f, 72);
  {
    long rows = (long)G * R1;
    softmax_bf16<<<(int)((rows + 3) / 4), 256, 0, stream>>>(RA, R1, rows);
    meang_bf16<<<(R1 * R1 + TPB - 1) / TPB, TPB, 0, stream>>>(RA, aw1, R1 * R1, G, 1.f / G);
  }
  LAUNCH_GEMM(true, true, false, 4, 232, RA, Vt, nullptr, W5,
              R1, 64, R1, R1, 64, (long)R1 * R1, (long)64 * Rpad1, (long)R1 * 64,
              G, 1.f, Rpad1);
  pool_mean_bf16<<<G, 256, 0, stream>>>(W5, Pz1, R1);

  // ======== attention branch, side 2 ========
  LAUNCH_GEMM(true, true, false, 8, 232, x2b, fcr1t, fcr1_b, RA,
              N2, 128, R2, XS, 128, 0, 0, 0, 1, 1.f, Kp2);
  LAUNCH_GEMM(true, true, false, 12, 136, RA, Wc2t, bc2, RB,
              N2, 192, 128, 128, 192, 0, 0, 0, 1, 1.f, 136);
  ktvt_kernel<<<G, 256, 0, stream>>>(RB, Kt, Vt, R2, Rpad2);
  LAUNCH_GEMM(true, true, false, 8, 72, RB, Kt, nullptr, RA,
              R2, R2, 64, 192, R2, (long)R2 * 192, (long)R2 * 72, (long)R2 * R2,
              G, 0.125f, 72);
  {
    long rows = (long)G * R2;
    softmax_bf16<<<(int)((rows + 3) / 4), 256, 0, stream>>>(RA, R2, rows);
    meang_bf16<<<(R2 * R2 + TPB - 1) / TPB, TPB, 0, stream>>>(RA, aw2, R2 * R2, G, 1.f / G);
  }
  LAUNCH_GEMM(true, true, false, 4, 232, RA, Vt, nullptr, W5,
              R2, 64, R2, R2, 64, (long)R2 * R2, (long)64 * Rpad2, (long)R2 * 64,
              G, 1.f, Rpad2);
  pool_mean_bf16<<<G, 256, 0, stream>>>(W5, Pz2, R2);

  // ======== GCN branch, side 1 (dense-adjacency MFMA form) ========
  unsigned short* hW0 = RB;
  unsigned short* hW1 = RB + (size_t)N1 * 64;
  unsigned short* hW2 = RB + (size_t)N1 * 128;
  LAUNCH_GEMM(true, true, false, 8, 232, x1b, fclt, fcl_b, RA,
              N1, 128, R1 + 3, XS, 128, 0, 0, 0, 1, 1.f, Kp1f);
  LAUNCH_GEMM(true, true, false, 4, 136, RA, convt, nullptr, hW0,
              N1, 64, 128, 128, 64, 0, 0, 0, 1, 1.f, 136);
  adj_build<<<G, 256, 0, stream>>>(ei1, ei1 + E1, Adj1, R1, Rpad1, EPG1);  // x1b dead
  transp64<<<G, 256, 0, stream>>>(hW0, Vt, R1, Rpad1);
  LAUNCH_GEMM(true, true, true, 4, 232, Adj1, Vt, convb, hW1,
              R1, 64, R1, Rpad1, 64, (long)R1 * Rpad1, (long)64 * Rpad1, (long)R1 * 64,
              G, 1.f, Rpad1);
  LAUNCH_GEMM(true, true, false, 4, 136, hW1, conv1t, nullptr, hW2,
              N1, 64, 64, 64, 64, 0, 0, 0, 1, 1.f, 72);
  transp64<<<G, 256, 0, stream>>>(hW2, Vt, R1, Rpad1);
  LAUNCH_GEMM(true, true, false, 4, 232, Adj1, Vt, conv1b, hW0,
              R1, 64, R1, Rpad1, 64, (long)R1 * Rpad1, (long)64 * Rpad1, (long)R1 * 64,
              G, 1.f, Rpad1);
  sub_mean_kernel<<<G, 64, 0, stream>>>(hW0, sub1, Mt, V);
  LAUNCH_GEMM(false, false, false, 4, 136, Mt, mlpt, mlpb, Ps1,
              G, 64, 64, 64, 64, 0, 0, 0, 1, 1.f, 72);

  // ======== GCN branch, side 2 ========
  LAUNCH_GEMM(true, true, false, 8, 232, x2b, fcrt, fcr_b, RA,
              N2, 128, R2 + 3, XS, 128, 0, 0, 0, 1, 1.f, Kp2f);
  LAUNCH_GEMM(true, true, false, 4, 136, RA, convt, nullptr, hW0,
              N2, 64, 128, 128, 64, 0, 0, 0, 1, 1.f, 136);
  adj_build<<<G, 256, 0, stream>>>(ei2, ei2 + E2, Adj2, R2, Rpad2, EPG2);  // x2b dead
  transp64<<<G, 256, 0, stream>>>(hW0, Vt, R2, Rpad2);
  LAUNCH_GEMM(true, true, true, 4, 232, Adj2, Vt, convb, hW1,
              R2, 64, R2, Rpad2, 64, (long)R2 * Rpad2, (long)64 * Rpad2, (long)R2 * 64,
              G, 1.f, Rpad2);
  LAUNCH_GEMM(true, true, false, 4, 136, hW1, conv1t, nullptr, hW2,
              N2, 64, 64, 64, 64, 0, 0, 0, 1, 1.f, 72);
  transp64<<<G, 256, 0, stream>>>(hW2, Vt, R2, Rpad2);
  LAUNCH_GEMM(true, true, false, 4, 232, Adj2, Vt, conv1b, hW0,
              R2, 64, R2, Rpad2, 64, (long)R2 * Rpad2, (long)64 * Rpad2, (long)R2 * 64,
              G, 1.f, Rpad2);
  sub_mean_kernel<<<G, 64, 0, stream>>>(hW0, sub2, Mt, V);
  LAUNCH_GEMM(false, false, false, 4, 136, Mt, mlpt, mlpb, Ps2,
              G, 64, 64, 64, 64, 0, 0, 0, 1, 1.f, 72);

  // ======== contrastive loss + head ========
  norm_rows_kernel<<<G, 64, 0, stream>>>(Ps1, n_s1);
  norm_rows_kernel<<<G, 64, 0, stream>>>(Pz2, n_z2);
  norm_rows_kernel<<<G, 64, 0, stream>>>(Pz1, n_z1);
  norm_rows_kernel<<<G, 64, 0, stream>>>(Ps2, n_s2);
  const float invTemp = 1.f / 0.6f;
  closs_kernel<<<G, 256, 0, stream>>>(n_s1, n_z2, loss, G, invTemp, 1.f / G);
  closs_kernel<<<G, 256, 0, stream>>>(n_z1, n_s2, loss, G, invTemp, 1.f / G);

  head_kernel<<<G, 128, 0, stream>>>(Ps1, Pz1, Ps2, Pz2, fc1aW, fc1ab, fc1bW, fc1bb, outp);
}

// Round 9
// 960.841 us; speedup vs baseline: 1.0482x; 1.0482x over previous
//
#include <hip/hip_runtime.h>
#include <math.h>

#define TPB 256
#define MAXEP 4608   // max padded CSR slots: E/G + R*7 <= 3200+1400=4600

typedef float f32x4 __attribute__((ext_vector_type(4)));
typedef __bf16 bfv8 __attribute__((ext_vector_type(8)));

union U8 { uint4 q; unsigned short us[8]; __bf16 b[8]; bfv8 v; };

__device__ __forceinline__ unsigned short f2bfu(float f) {
  union { __bf16 h; unsigned short u; } x;
  x.h = (__bf16)f;
  return x.u;
}
__device__ __forceinline__ float bfu2f(unsigned short u) {
  return __uint_as_float((unsigned)u << 16);
}

__device__ __forceinline__ float mish_f(float x) {
  float sp = fmaxf(x, 0.f) + log1pf(expf(-fabsf(x)));
  return x * tanhf(sp);
}

// ---------------------------------------------------------------------------
// gemm2 (R6-verified): C = alpha*(A @ Bt^T) + bias [, mish].
// A (N,lda) bf16 (lda mult-8 -> unconditional uint4 frags) or fp32 (any lda,
// in-register bf16 convert, guarded tail). Bt contiguous bf16 (M,Kpad) panel,
// zero-padded in k. Kpad%16==8.
// ---------------------------------------------------------------------------
__device__ __forceinline__ U8 loadA_f32(const float* Af, int kb, int K, bool rowok) {
  U8 u;
  if (rowok && kb + 8 <= K) {
    float4 f0 = *(const float4*)(Af + kb);
    float4 f1 = *(const float4*)(Af + kb + 4);
    u.b[0]=(__bf16)f0.x; u.b[1]=(__bf16)f0.y; u.b[2]=(__bf16)f0.z; u.b[3]=(__bf16)f0.w;
    u.b[4]=(__bf16)f1.x; u.b[5]=(__bf16)f1.y; u.b[6]=(__bf16)f1.z; u.b[7]=(__bf16)f1.w;
  } else {
#pragma unroll
    for (int j = 0; j < 8; ++j) {
      float f = (rowok && kb + j < K) ? Af[kb + j] : 0.f;
      u.b[j] = (__bf16)f;
    }
  }
  return u;
}

template<bool ABF16, bool CBF16, bool MISH, int NJ, int KPMAX>
__global__ __launch_bounds__(256) void gemm2(
    const void* __restrict__ Av, const unsigned short* __restrict__ Bt,
    const float* __restrict__ bias, void* __restrict__ Cv,
    int N, int M, int K, int lda, int ldc,
    long sA, long sB, long sC, float alpha, int Kpad)
{
  constexpr int BM = NJ * 16;
  __shared__ unsigned short Bs[BM * KPMAX];

  const int tid = threadIdx.x;
  const int col0 = blockIdx.x * BM, row0 = blockIdx.y * 64;

  // ---- stage B panel: contiguous uint4 copy, 4-deep ----
  {
    const unsigned short* Bp = Bt + (long)blockIdx.z * sB + (long)col0 * Kpad;
    int rows = M - col0; if (rows > BM) rows = BM;
    const int total = rows * Kpad;
    for (int i = tid * 8; i < total; i += TPB * 32) {
      uint4 a0, a1, a2, a3;
      bool b1 = i + TPB * 8  < total;
      bool b2 = i + TPB * 16 < total;
      bool b3 = i + TPB * 24 < total;
      a0 = *(const uint4*)&Bp[i];
      if (b1) a1 = *(const uint4*)&Bp[i + TPB * 8];
      if (b2) a2 = *(const uint4*)&Bp[i + TPB * 16];
      if (b3) a3 = *(const uint4*)&Bp[i + TPB * 24];
      *(uint4*)&Bs[i] = a0;
      if (b1) *(uint4*)&Bs[i + TPB * 8]  = a1;
      if (b2) *(uint4*)&Bs[i + TPB * 16] = a2;
      if (b3) *(uint4*)&Bs[i + TPB * 24] = a3;
    }
  }

  const int lane = tid & 63, w = tid >> 6;
  const int mrow = lane & 15, kg = lane >> 4;
  const int arow = row0 + w * 16 + mrow;
  const bool rowok = arow < N;

  const unsigned short* Ah = nullptr;
  const float* Af = nullptr;
  if (ABF16) Ah = (const unsigned short*)Av + (long)blockIdx.z * sA + (long)arow * lda;
  else       Af = (const float*)Av + (long)blockIdx.z * sA + (long)arow * lda;

  U8 ua;
  if (ABF16) ua.q = *(const uint4*)(Ah + kg * 8);
  else       ua   = loadA_f32(Af, kg * 8, K, rowok);

  __syncthreads();

  f32x4 acc[NJ];
#pragma unroll
  for (int j = 0; j < NJ; ++j) acc[j] = (f32x4)0.f;

  for (int k0 = 0; k0 < K; k0 += 32) {
    U8 un;
    bool more = (k0 + 32) < K;
    if (more) {
      if (ABF16) un.q = *(const uint4*)(Ah + k0 + 32 + kg * 8);
      else       un   = loadA_f32(Af, k0 + 32 + kg * 8, K, rowok);
    }
    const int kb = k0 + kg * 8;
#pragma unroll
    for (int j = 0; j < NJ; ++j) {
      U8 ub;
      ub.q = *(const uint4*)&Bs[(j * 16 + mrow) * Kpad + kb];
      acc[j] = __builtin_amdgcn_mfma_f32_16x16x32_bf16(ua.v, ub.v, acc[j], 0, 0, 0);
    }
    if (more) ua = un;
  }

  long cbase = (long)blockIdx.z * sC;
#pragma unroll
  for (int j = 0; j < NJ; ++j) {
    int gc = col0 + j * 16 + mrow;
    if (gc >= M) continue;
    float bb = bias ? bias[gc] : 0.f;
#pragma unroll
    for (int r = 0; r < 4; ++r) {
      int gr = row0 + w * 16 + kg * 4 + r;
      if (gr >= N) continue;
      float v = acc[j][r] * alpha + bb;
      if (MISH) v = mish_f(v);
      if (CBF16) ((unsigned short*)Cv)[cbase + (long)gr * ldc + gc] = f2bfu(v);
      else       ((float*)Cv)[cbase + (long)gr * ldc + gc] = v;
    }
  }
}

static inline int kpad_of(int K) { return ((K + 31) / 32) * 32 + 8; }

// ---------------------------------------------------------------------------
// prep: weights -> pre-transposed bf16 (M,Kpad) panels; bias concat.
// ---------------------------------------------------------------------------
struct PrepSeg { const float* src; void* dst; int K, M, Kpad, kind; };
struct PrepArgs { PrepSeg s[19]; };

__global__ __launch_bounds__(256) void prep_weights(PrepArgs a) {
  PrepSeg sg = a.s[blockIdx.x];
  if (sg.kind == 0) {
    unsigned short* d = (unsigned short*)sg.dst;
    int tot = sg.M * sg.Kpad;
    for (int i = threadIdx.x; i < tot; i += TPB) {
      int m = i / sg.Kpad, k = i - m * sg.Kpad;
      float f = (k < sg.K) ? sg.src[(long)k * sg.M + m] : 0.f;
      d[i] = f2bfu(f);
    }
  } else {
    float* d = (float*)sg.dst;
    for (int i = threadIdx.x; i < sg.K; i += TPB) d[i] = sg.src[i];
  }
}

// ---------------------------------------------------------------------------
// ktvt2: per-graph Kt (R,72) contiguous bf16 slice of K (coalesced copy) and
// Vt (64,Rpad) = V^T via 64x64 LDS tile (coalesced reads AND 16B writes).
// Replaces the 2B-scatter Vt write of the old ktvt (R8 latency sink).
// ---------------------------------------------------------------------------
__global__ __launch_bounds__(256) void ktvt2(
    const unsigned short* __restrict__ QKV, unsigned short* __restrict__ Kt,
    unsigned short* __restrict__ Vt, int R, int Rpad)
{
  __shared__ unsigned short tile[64][72];
  int g = blockIdx.x, tid = threadIdx.x;
  const unsigned short* q = QKV + (long)g * R * 192;
  unsigned short* kt = Kt + (long)g * R * 72;
  unsigned short* vt = Vt + (long)g * 64 * Rpad;

  // Kt copy: row r cols 0..63 <- K slice (contiguous 128B per wave)
  {
    int c = tid & 63, w = tid >> 6;
    for (int r = w; r < R; r += 4)
      kt[r * 72 + c] = q[(long)r * 192 + 64 + c];
  }

  // Vt transpose via LDS tiles
  for (int r0 = 0; r0 < Rpad; r0 += 64) {
    __syncthreads();
    for (int i = tid; i < 64 * 64; i += TPB) {
      int rr = i >> 6, cc = i & 63;
      int r = r0 + rr;
      tile[cc][rr] = (r < R) ? q[(long)r * 192 + 128 + cc] : (unsigned short)0;
    }
    __syncthreads();
    int c = tid >> 2, j0 = (tid & 3) * 16;
    int lim = Rpad - r0; if (lim > 64) lim = 64;
    for (int jj = j0; jj < j0 + 16 && jj < lim; jj += 8) {
      uint4 qv = *(const uint4*)&tile[c][jj];
      *(uint4*)&vt[(long)c * Rpad + r0 + jj] = qv;
    }
  }
}

// ---------------------------------------------------------------------------
// adj_build (R8-verified): dense normalized adjacency per graph, bf16
// (R x Rpad), self-loop folded. A[d][s] = dinv[d]*dinv[s]*cnt + (s==d)*dinv^2.
// ---------------------------------------------------------------------------
__global__ __launch_bounds__(256) void adj_build(
    const int* __restrict__ src, const int* __restrict__ dst,
    unsigned short* __restrict__ Adj, int R, int Rpad, int EPG)
{
  __shared__ float dinv_s[256];
  __shared__ unsigned short ssrc[MAXEP];
  __shared__ int cnt[256];
  __shared__ int scan[256];
  __shared__ int offx[257];
  __shared__ int cur[256];
  __shared__ float rowbuf[4][256];

  int g = blockIdx.x, tid = threadIdx.x;
  long ebase = (long)g * EPG;
  int gR = g * R;

  cnt[tid] = 0;
  __syncthreads();
  for (int e = tid; e < EPG; e += TPB)
    atomicAdd(&cnt[dst[ebase + e] - gR], 1);
  __syncthreads();

  int x = cnt[tid];
  int pc = (x + 7) & ~7;
  scan[tid] = pc;
  __syncthreads();
#pragma unroll
  for (int s = 1; s < 256; s <<= 1) {
    int t = (tid >= s) ? scan[tid - s] : 0;
    __syncthreads();
    scan[tid] += t;
    __syncthreads();
  }
  if (tid == 0) offx[0] = 0;
  offx[tid + 1] = scan[tid];
  cur[tid] = scan[tid] - pc;
  dinv_s[tid] = rsqrtf((float)x + 1.f);
  {
    unsigned dummy2 = 0xFFFFFFFFu;   // 0xFFFF > R -> guarded out
    for (int i = tid; i < MAXEP / 2; i += TPB) ((unsigned*)ssrc)[i] = dummy2;
  }
  __syncthreads();

  for (int e = tid; e < EPG; e += TPB) {
    int d = dst[ebase + e] - gR;
    int s = src[ebase + e] - gR;
    int pos = atomicAdd(&cur[d], 1);
    ssrc[pos] = (unsigned short)s;
  }
  __syncthreads();

  int lane = tid & 63, w = tid >> 6;
  float* rb = rowbuf[w];
  for (int d = w; d < R; d += 4) {
#pragma unroll
    for (int i = 0; i < 4; ++i) rb[lane + i * 64] = 0.f;
    int i0 = offx[d], i1 = offx[d + 1];
    for (int i = i0 + lane; i < i1; i += 64) {
      int s = ssrc[i];
      if (s < R) atomicAdd(&rb[s], dinv_s[s]);
    }
    float dd = dinv_s[d];
    int c0 = lane * 4;
    if (c0 < Rpad) {
      ushort4 o;
      float v0 = rb[c0]     + (c0     == d ? dd : 0.f);
      float v1 = rb[c0 + 1] + (c0 + 1 == d ? dd : 0.f);
      float v2 = rb[c0 + 2] + (c0 + 2 == d ? dd : 0.f);
      float v3 = rb[c0 + 3] + (c0 + 3 == d ? dd : 0.f);
      o.x = f2bfu(v0 * dd); o.y = f2bfu(v1 * dd);
      o.z = f2bfu(v2 * dd); o.w = f2bfu(v3 * dd);
      *(ushort4*)&Adj[((long)gR + d) * Rpad + c0] = o;
    }
  }
}

// transp64: per-graph (R x 64) bf16 -> (64 x Rpad) bf16, zero-padded cols>=R.
__global__ __launch_bounds__(256) void transp64(
    const unsigned short* __restrict__ X, unsigned short* __restrict__ XT,
    int R, int Rpad)
{
  __shared__ unsigned short tile[64][72];
  int g = blockIdx.x, tid = threadIdx.x;
  const unsigned short* xg = X + (long)g * R * 64;
  unsigned short* xt = XT + (long)g * 64 * Rpad;
  for (int r0 = 0; r0 < Rpad; r0 += 64) {
    __syncthreads();
    for (int i = tid; i < 64 * 64; i += TPB) {
      int rr = i >> 6, cc = i & 63;
      int r = r0 + rr;
      tile[cc][rr] = (r < R) ? xg[(long)r * 64 + cc] : (unsigned short)0;
    }
    __syncthreads();
    int c = tid >> 2, j0 = (tid & 3) * 16;
    int lim = Rpad - r0; if (lim > 64) lim = 64;
    for (int jj = j0; jj < j0 + 16 && jj < lim; jj += 8) {
      uint4 q = *(const uint4*)&tile[c][jj];
      *(uint4*)&xt[(long)c * Rpad + r0 + jj] = q;
    }
  }
}

// wave-per-row softmax in place on bf16; row length R <= 256
__global__ __launch_bounds__(256) void softmax_bf16(unsigned short* __restrict__ S,
                                                    int R, long rows)
{
  long wid = (long)blockIdx.x * 4 + (threadIdx.x >> 6);
  if (wid >= rows) return;
  int lane = threadIdx.x & 63;
  unsigned short* row = S + wid * R;
  float v[4];
  float mx = -1e30f;
#pragma unroll
  for (int t = 0; t < 4; ++t) {
    int j = lane + t * 64;
    v[t] = (j < R) ? bfu2f(row[j]) : -1e30f;
    mx = fmaxf(mx, v[t]);
  }
#pragma unroll
  for (int o = 32; o; o >>= 1) mx = fmaxf(mx, __shfl_xor(mx, o));
  float s = 0.f;
#pragma unroll
  for (int t = 0; t < 4; ++t) {
    int j = lane + t * 64;
    if (j < R) { v[t] = expf(v[t] - mx); s += v[t]; }
  }
#pragma unroll
  for (int o = 32; o; o >>= 1) s += __shfl_xor(s, o);
  float inv = 1.f / s;
#pragma unroll
  for (int t = 0; t < 4; ++t) {
    int j = lane + t * 64;
    if (j < R) row[j] = f2bfu(v[t] * inv);
  }
}

// out[idx] = inv * sum_g S[g*RR + idx]; 8-way unrolled
__global__ void meang_bf16(const unsigned short* __restrict__ S, float* __restrict__ out,
                           int RR, int G, float inv)
{
  int idx = blockIdx.x * TPB + threadIdx.x;
  if (idx >= RR) return;
  const unsigned short* p = S + idx;
  float s = 0.f;
  for (int g = 0; g + 8 <= G; g += 8) {
    s += bfu2f(p[(long)g * RR])       + bfu2f(p[(long)(g + 1) * RR]) +
         bfu2f(p[(long)(g + 2) * RR]) + bfu2f(p[(long)(g + 3) * RR]) +
         bfu2f(p[(long)(g + 4) * RR]) + bfu2f(p[(long)(g + 5) * RR]) +
         bfu2f(p[(long)(g + 6) * RR]) + bfu2f(p[(long)(g + 7) * RR]);
  }
  out[idx] = s * inv;
}

// per-graph mean over R rows (bf16 in). grid=G, 256 threads.
__global__ __launch_bounds__(256) void pool_mean_bf16(const unsigned short* __restrict__ X,
                                                      float* __restrict__ out, int R)
{
  __shared__ float part[4][64];
  int g = blockIdx.x, lane = threadIdx.x & 63, w = threadIdx.x >> 6;
  float s = 0.f;
  for (int r = w; r < R; r += 4)
    s += bfu2f(X[((long)g * R + r) * 64 + lane]);
  part[w][lane] = s;
  __syncthreads();
  if (w == 0)
    out[g * 64 + lane] = (part[0][lane] + part[1][lane] + part[2][lane] + part[3][lane]) * (1.f / R);
}

// per-graph mean over V gathered rows (bf16 in). grid=G, 64 threads.
__global__ __launch_bounds__(64) void sub_mean_kernel(const unsigned short* __restrict__ X,
                                                      const int* __restrict__ sub,
                                                      float* __restrict__ out, int V)
{
  int g = blockIdx.x, lane = threadIdx.x;
  float s = 0.f;
  for (int v = 0; v + 4 <= V; v += 4) {
    int i0 = sub[g * V + v],     i1 = sub[g * V + v + 1];
    int i2 = sub[g * V + v + 2], i3 = sub[g * V + v + 3];
    s += bfu2f(X[(long)i0 * 64 + lane]) + bfu2f(X[(long)i1 * 64 + lane]) +
         bfu2f(X[(long)i2 * 64 + lane]) + bfu2f(X[(long)i3 * 64 + lane]);
  }
  out[g * 64 + lane] = s * (1.f / V);
}

__global__ __launch_bounds__(64) void norm_rows_kernel(const float* __restrict__ X,
                                                       float* __restrict__ Y)
{
  int g = blockIdx.x, lane = threadIdx.x;
  float x = X[g * 64 + lane];
  float ss = x * x;
#pragma unroll
  for (int o = 32; o; o >>= 1) ss += __shfl_xor(ss, o);
  float n = fmaxf(sqrtf(ss), 1e-12f);
  Y[g * 64 + lane] = x / n;
}

__global__ __launch_bounds__(256) void closs_kernel(const float* __restrict__ An,
                                                    const float* __restrict__ Bn,
                                                    float* __restrict__ loss, int G,
                                                    float invTemp, float coef)
{
  int i = blockIdx.x;
  __shared__ float arow[64];
  __shared__ float logits[512];
  __shared__ float red[256];
  int t = threadIdx.x;
  if (t < 64) arow[t] = An[i * 64 + t];
  __syncthreads();
  for (int j = t; j < G; j += 256) {
    const float* bp = Bn + (long)j * 64;
    float d = 0.f;
#pragma unroll
    for (int k = 0; k < 64; ++k) d = fmaf(arow[k], bp[k], d);
    logits[j] = d * invTemp;
  }
  __syncthreads();
  float mx = -1e30f;
  for (int j = t; j < G; j += 256) mx = fmaxf(mx, logits[j]);
  red[t] = mx; __syncthreads();
  for (int o = 128; o; o >>= 1) { if (t < o) red[t] = fmaxf(red[t], red[t + o]); __syncthreads(); }
  mx = red[0]; __syncthreads();
  float s = 0.f;
  for (int j = t; j < G; j += 256) s += expf(logits[j] - mx);
  red[t] = s; __syncthreads();
  for (int o = 128; o; o >>= 1) { if (t < o) red[t] += red[t + o]; __syncthreads(); }
  if (t == 0) {
    float lse = mx + logf(red[0]);
    atomicAdd(loss, coef * (lse - logits[i]));
  }
}

__global__ __launch_bounds__(128) void head_kernel(
    const float* __restrict__ s1, const float* __restrict__ z1,
    const float* __restrict__ s2, const float* __restrict__ z2,
    const float* __restrict__ W1, const float* __restrict__ b1,
    const float* __restrict__ W2, const float* __restrict__ b2,
    float* __restrict__ out)
{
  int g = blockIdx.x, t = threadIdx.x;
  __shared__ float feat[256];
  __shared__ float hid[128];
  if (t < 64) {
    feat[t]       = s1[g * 64 + t];
    feat[64 + t]  = z1[g * 64 + t];
    feat[128 + t] = s2[g * 64 + t];
    feat[192 + t] = z2[g * 64 + t];
  }
  __syncthreads();
  float acc = b1[t];
  for (int k = 0; k < 256; ++k) acc = fmaf(feat[k], W1[k * 128 + t], acc);
  hid[t] = mish_f(acc);
  __syncthreads();
  if (t < 2) {
    float a2 = b2[t];
#pragma unroll
    for (int k = 0; k < 128; ++k) a2 = fmaf(hid[k], W2[k * 2 + t], a2);
    out[g * 2 + t] = a2;
  }
}

#define LAUNCH_GEMM(ABF,CBF,MISH,NJ,KP, A,B,BI,C, N,M,K,LDA,LDC,SA,SB,SC,BAT,AL,KPAD) \
  { dim3 g_(((M)+(NJ)*16-1)/((NJ)*16), ((N)+63)/64, (BAT)); \
    gemm2<ABF,CBF,MISH,NJ,KP><<<g_,256,0,stream>>>((A),(B),(BI),(C),(N),(M),(K),(LDA),(LDC),(SA),(SB),(SC),(AL),(KPAD)); }

extern "C" void kernel_launch(void* const* d_in, const int* in_sizes, int n_in,
                              void* d_out, int out_size, void* d_ws, size_t ws_size,
                              hipStream_t stream)
{
  const float* x1     = (const float*)d_in[0];
  const float* x2     = (const float*)d_in[1];
  const float* fcl_W  = (const float*)d_in[2];  const float* fcl_b  = (const float*)d_in[3];
  const float* fcr_W  = (const float*)d_in[4];  const float* fcr_b  = (const float*)d_in[5];
  const float* fcl1_W = (const float*)d_in[6];  const float* fcl1_b = (const float*)d_in[7];
  const float* fcr1_W = (const float*)d_in[8];  const float* fcr1_b = (const float*)d_in[9];
  const float* a1qW = (const float*)d_in[10]; const float* a1qb = (const float*)d_in[11];
  const float* a1kW = (const float*)d_in[12]; const float* a1kb = (const float*)d_in[13];
  const float* a1vW = (const float*)d_in[14]; const float* a1vb = (const float*)d_in[15];
  const float* a2qW = (const float*)d_in[16]; const float* a2qb = (const float*)d_in[17];
  const float* a2kW = (const float*)d_in[18]; const float* a2kb = (const float*)d_in[19];
  const float* a2vW = (const float*)d_in[20]; const float* a2vb = (const float*)d_in[21];
  const float* convW  = (const float*)d_in[22]; const float* convb  = (const float*)d_in[23];
  const float* conv1W = (const float*)d_in[24]; const float* conv1b = (const float*)d_in[25];
  const float* mlpW   = (const float*)d_in[26]; const float* mlpb   = (const float*)d_in[27];
  const float* fc1aW  = (const float*)d_in[28]; const float* fc1ab  = (const float*)d_in[29];
  const float* fc1bW  = (const float*)d_in[30]; const float* fc1bb  = (const float*)d_in[31];
  const int* ei1  = (const int*)d_in[32];
  const int* ei2  = (const int*)d_in[33];
  const int* sub1 = (const int*)d_in[36];
  const int* sub2 = (const int*)d_in[37];

  const int R1 = in_sizes[6] / 128;       // 200
  const int R2 = in_sizes[8] / 128;       // 160
  const int N1 = in_sizes[34];            // 102400
  const int N2 = in_sizes[35];            // 81920
  const int G  = N1 / R1;                 // 512
  const int E1 = in_sizes[32] / 2, E2 = in_sizes[33] / 2;
  const int EPG1 = E1 / G, EPG2 = E2 / G;
  const int V = in_sizes[36] / G;

  const int Kp1  = kpad_of(R1);           // 232
  const int Kp2  = kpad_of(R2);           // 168
  const int Kp1f = kpad_of(R1 + 3);       // 232
  const int Kp2f = kpad_of(R2 + 3);       // 200
  const int Rpad1 = Kp1, Rpad2 = Kp2;

  // ---------------- workspace layout ----------------
  char* wp = (char*)d_ws;
  auto alloc = [&](size_t bytes) -> char* {
    char* p = wp; wp += (bytes + 255) & ~(size_t)255; return p;
  };
  size_t raSh = (size_t)G * R1 * R1;
  if ((size_t)N1 * 128 > raSh) raSh = (size_t)N1 * 128;
  unsigned short* RA = (unsigned short*)alloc(raSh * 2);
  unsigned short* RB = (unsigned short*)alloc((size_t)N1 * 192 * 2);
  unsigned short* Kt = (unsigned short*)alloc((size_t)G * R1 * 72 * 2);
  unsigned short* Vt = (unsigned short*)alloc((size_t)G * 64 * Rpad1 * 2);  // also hW^T
  unsigned short* W5 = (unsigned short*)alloc((size_t)N1 * 64 * 2);         // PV out bf16
  unsigned short* Adj1 = (unsigned short*)alloc((size_t)G * R1 * Rpad1 * 2);
  unsigned short* Adj2 = (unsigned short*)alloc((size_t)G * R2 * Rpad2 * 2);
  unsigned short* fcl1t  = (unsigned short*)alloc((size_t)128 * Kp1 * 2);
  unsigned short* fcr1t  = (unsigned short*)alloc((size_t)128 * Kp2 * 2);
  unsigned short* fclt   = (unsigned short*)alloc((size_t)128 * Kp1f * 2);
  unsigned short* fcrt   = (unsigned short*)alloc((size_t)128 * Kp2f * 2);
  unsigned short* Wc1t   = (unsigned short*)alloc((size_t)192 * 136 * 2);
  unsigned short* Wc2t   = (unsigned short*)alloc((size_t)192 * 136 * 2);
  unsigned short* convt  = (unsigned short*)alloc((size_t)64 * 136 * 2);
  unsigned short* conv1t = (unsigned short*)alloc((size_t)64 * 72 * 2);
  unsigned short* mlpt   = (unsigned short*)alloc((size_t)64 * 72 * 2);
  float* bc1 = (float*)alloc(192 * 4);
  float* bc2 = (float*)alloc(192 * 4);
  float* Pz1 = (float*)alloc((size_t)G * 64 * 4);
  float* Pz2 = (float*)alloc((size_t)G * 64 * 4);
  float* Ps1 = (float*)alloc((size_t)G * 64 * 4);
  float* Ps2 = (float*)alloc((size_t)G * 64 * 4);
  float* Mt  = (float*)alloc((size_t)G * 64 * 4);
  float* n_s1 = (float*)alloc((size_t)G * 64 * 4);
  float* n_z2 = (float*)alloc((size_t)G * 64 * 4);
  float* n_z1 = (float*)alloc((size_t)G * 64 * 4);
  float* n_s2 = (float*)alloc((size_t)G * 64 * 4);
  (void)alloc(65536);   // tail slack for benign bf16-A row overreads

  float* loss = (float*)d_out;
  float* outp = loss + 1;
  float* aw1  = outp + (size_t)G * 2;
  float* aw2  = aw1 + (size_t)R1 * R1;

  hipMemsetAsync(d_out, 0, sizeof(float), stream);

  // ---------------- prep ----------------
  PrepArgs pa;
  int seg = 0;
  auto addp = [&](const float* s, unsigned short* d, int K, int M, int Kp) {
    pa.s[seg].src = s; pa.s[seg].dst = d; pa.s[seg].K = K; pa.s[seg].M = M;
    pa.s[seg].Kpad = Kp; pa.s[seg].kind = 0; seg++;
  };
  auto addb = [&](const float* s, float* d, int n) {
    pa.s[seg].src = s; pa.s[seg].dst = d; pa.s[seg].K = n; pa.s[seg].M = 0;
    pa.s[seg].Kpad = 0; pa.s[seg].kind = 1; seg++;
  };
  addp(fcl1_W, fcl1t, R1, 128, Kp1);
  addp(fcr1_W, fcr1t, R2, 128, Kp2);
  addp(fcl_W,  fclt,  R1 + 3, 128, Kp1f);
  addp(fcr_W,  fcrt,  R2 + 3, 128, Kp2f);
  addp(a1qW, Wc1t,             128, 64, 136);
  addp(a1kW, Wc1t + 64 * 136,  128, 64, 136);
  addp(a1vW, Wc1t + 128 * 136, 128, 64, 136);
  addp(a2qW, Wc2t,             128, 64, 136);
  addp(a2kW, Wc2t + 64 * 136,  128, 64, 136);
  addp(a2vW, Wc2t + 128 * 136, 128, 64, 136);
  addp(convW,  convt,  128, 64, 136);
  addp(conv1W, conv1t, 64, 64, 72);
  addp(mlpW,   mlpt,   64, 64, 72);
  addb(a1qb, bc1, 64); addb(a1kb, bc1 + 64, 64); addb(a1vb, bc1 + 128, 64);
  addb(a2qb, bc2, 64); addb(a2kb, bc2 + 64, 64); addb(a2vb, bc2 + 128, 64);
  prep_weights<<<seg, 256, 0, stream>>>(pa);

  // ======== attention branch, side 1 (x1 fp32 direct) ========
  LAUNCH_GEMM(false, true, false, 8, 232, x1, fcl1t, fcl1_b, RA,
              N1, 128, R1, R1 + 3, 128, 0, 0, 0, 1, 1.f, Kp1);
  LAUNCH_GEMM(true, true, false, 12, 136, RA, Wc1t, bc1, RB,
              N1, 192, 128, 128, 192, 0, 0, 0, 1, 1.f, 136);
  ktvt2<<<G, 256, 0, stream>>>(RB, Kt, Vt, R1, Rpad1);
  LAUNCH_GEMM(true, true, false, 8, 72, RB, Kt, nullptr, RA,
              R1, R1, 64, 192, R1, (long)R1 * 192, (long)R1 * 72, (long)R1 * R1,
              G, 0.125f, 72);
  {
    long rows = (long)G * R1;
    softmax_bf16<<<(int)((rows + 3) / 4), 256, 0, stream>>>(RA, R1, rows);
    meang_bf16<<<(R1 * R1 + TPB - 1) / TPB, TPB, 0, stream>>>(RA, aw1, R1 * R1, G, 1.f / G);
  }
  LAUNCH_GEMM(true, true, false, 4, 232, RA, Vt, nullptr, W5,
              R1, 64, R1, R1, 64, (long)R1 * R1, (long)64 * Rpad1, (long)R1 * 64,
              G, 1.f, Rpad1);
  pool_mean_bf16<<<G, 256, 0, stream>>>(W5, Pz1, R1);

  // ======== attention branch, side 2 (x2 fp32 direct) ========
  LAUNCH_GEMM(false, true, false, 8, 232, x2, fcr1t, fcr1_b, RA,
              N2, 128, R2, R2 + 3, 128, 0, 0, 0, 1, 1.f, Kp2);
  LAUNCH_GEMM(true, true, false, 12, 136, RA, Wc2t, bc2, RB,
              N2, 192, 128, 128, 192, 0, 0, 0, 1, 1.f, 136);
  ktvt2<<<G, 256, 0, stream>>>(RB, Kt, Vt, R2, Rpad2);
  LAUNCH_GEMM(true, true, false, 8, 72, RB, Kt, nullptr, RA,
              R2, R2, 64, 192, R2, (long)R2 * 192, (long)R2 * 72, (long)R2 * R2,
              G, 0.125f, 72);
  {
    long rows = (long)G * R2;
    softmax_bf16<<<(int)((rows + 3) / 4), 256, 0, stream>>>(RA, R2, rows);
    meang_bf16<<<(R2 * R2 + TPB - 1) / TPB, TPB, 0, stream>>>(RA, aw2, R2 * R2, G, 1.f / G);
  }
  LAUNCH_GEMM(true, true, false, 4, 232, RA, Vt, nullptr, W5,
              R2, 64, R2, R2, 64, (long)R2 * R2, (long)64 * Rpad2, (long)R2 * 64,
              G, 1.f, Rpad2);
  pool_mean_bf16<<<G, 256, 0, stream>>>(W5, Pz2, R2);

  // ======== GCN branch, side 1 (dense-adjacency MFMA form) ========
  unsigned short* hW0 = RB;
  unsigned short* hW1 = RB + (size_t)N1 * 64;
  unsigned short* hW2 = RB + (size_t)N1 * 128;
  LAUNCH_GEMM(false, true, false, 8, 232, x1, fclt, fcl_b, RA,
              N1, 128, R1 + 3, R1 + 3, 128, 0, 0, 0, 1, 1.f, Kp1f);
  LAUNCH_GEMM(true, true, false, 4, 136, RA, convt, nullptr, hW0,
              N1, 64, 128, 128, 64, 0, 0, 0, 1, 1.f, 136);
  adj_build<<<G, 256, 0, stream>>>(ei1, ei1 + E1, Adj1, R1, Rpad1, EPG1);
  transp64<<<G, 256, 0, stream>>>(hW0, Vt, R1, Rpad1);
  LAUNCH_GEMM(true, true, true, 4, 232, Adj1, Vt, convb, hW1,
              R1, 64, R1, Rpad1, 64, (long)R1 * Rpad1, (long)64 * Rpad1, (long)R1 * 64,
              G, 1.f, Rpad1);
  LAUNCH_GEMM(true, true, false, 4, 136, hW1, conv1t, nullptr, hW2,
              N1, 64, 64, 64, 64, 0, 0, 0, 1, 1.f, 72);
  transp64<<<G, 256, 0, stream>>>(hW2, Vt, R1, Rpad1);
  LAUNCH_GEMM(true, true, false, 4, 232, Adj1, Vt, conv1b, hW0,
              R1, 64, R1, Rpad1, 64, (long)R1 * Rpad1, (long)64 * Rpad1, (long)R1 * 64,
              G, 1.f, Rpad1);
  sub_mean_kernel<<<G, 64, 0, stream>>>(hW0, sub1, Mt, V);
  LAUNCH_GEMM(false, false, false, 4, 136, Mt, mlpt, mlpb, Ps1,
              G, 64, 64, 64, 64, 0, 0, 0, 1, 1.f, 72);

  // ======== GCN branch, side 2 ========
  LAUNCH_GEMM(false, true, false, 8, 232, x2, fcrt, fcr_b, RA,
              N2, 128, R2 + 3, R2 + 3, 128, 0, 0, 0, 1, 1.f, Kp2f);
  LAUNCH_GEMM(true, true, false, 4, 136, RA, convt, nullptr, hW0,
              N2, 64, 128, 128, 64, 0, 0, 0, 1, 1.f, 136);
  adj_build<<<G, 256, 0, stream>>>(ei2, ei2 + E2, Adj2, R2, Rpad2, EPG2);
  transp64<<<G, 256, 0, stream>>>(hW0, Vt, R2, Rpad2);
  LAUNCH_GEMM(true, true, true, 4, 232, Adj2, Vt, convb, hW1,
              R2, 64, R2, Rpad2, 64, (long)R2 * Rpad2, (long)64 * Rpad2, (long)R2 * 64,
              G, 1.f, Rpad2);
  LAUNCH_GEMM(true, true, false, 4, 136, hW1, conv1t, nullptr, hW2,
              N2, 64, 64, 64, 64, 0, 0, 0, 1, 1.f, 72);
  transp64<<<G, 256, 0, stream>>>(hW2, Vt, R2, Rpad2);
  LAUNCH_GEMM(true, true, false, 4, 232, Adj2, Vt, conv1b, hW0,
              R2, 64, R2, Rpad2, 64, (long)R2 * Rpad2, (long)64 * Rpad2, (long)R2 * 64,
              G, 1.f, Rpad2);
  sub_mean_kernel<<<G, 64, 0, stream>>>(hW0, sub2, Mt, V);
  LAUNCH_GEMM(false, false, false, 4, 136, Mt, mlpt, mlpb, Ps2,
              G, 64, 64, 64, 64, 0, 0, 0, 1, 1.f, 72);

  // ======== contrastive loss + head ========
  norm_rows_kernel<<<G, 64, 0, stream>>>(Ps1, n_s1);
  norm_rows_kernel<<<G, 64, 0, stream>>>(Pz2, n_z2);
  norm_rows_kernel<<<G, 64, 0, stream>>>(Pz1, n_z1);
  norm_rows_kernel<<<G, 64, 0, stream>>>(Ps2, n_s2);
  const float invTemp = 1.f / 0.6f;
  closs_kernel<<<G, 256, 0, stream>>>(n_s1, n_z2, loss, G, invTemp, 1.f / G);
  closs_kernel<<<G, 256, 0, stream>>>(n_z1, n_s2, loss, G, invTemp, 1.f / G);

  head_kernel<<<G, 128, 0, stream>>>(Ps1, Pz1, Ps2, Pz2, fc1aW, fc1ab, fc1bW, fc1bb, outp);
}

// Round 10
// 952.963 us; speedup vs baseline: 1.0568x; 1.0083x over previous
//
#include <hip/hip_runtime.h>
#include <math.h>

#define TPB 256
#define MAXEP 4608   // max padded CSR slots: E/G + R*7 <= 3200+1400=4600

typedef float f32x4 __attribute__((ext_vector_type(4)));
typedef __bf16 bfv8 __attribute__((ext_vector_type(8)));

union U8 { uint4 q; unsigned short us[8]; __bf16 b[8]; bfv8 v; };

__device__ __forceinline__ unsigned short f2bfu(float f) {
  union { __bf16 h; unsigned short u; } x;
  x.h = (__bf16)f;
  return x.u;
}
__device__ __forceinline__ float bfu2f(unsigned short u) {
  return __uint_as_float((unsigned)u << 16);
}

__device__ __forceinline__ float mish_f(float x) {
  float sp = fmaxf(x, 0.f) + log1pf(expf(-fabsf(x)));
  return x * tanhf(sp);
}

// ---------------------------------------------------------------------------
// gemm2 (R6-verified): C = alpha*(A @ Bt^T) + bias [, mish].
// A (N,lda) bf16 (lda mult-8 -> unconditional uint4 frags) or fp32 (any lda,
// in-register bf16 convert, guarded tail). Bt contiguous bf16 (M,Kpad) panel,
// zero-padded in k. Kpad%16==8; kpad_of() guarantees all MFMA k-reads land
// inside the zero-padded panel (R3 lesson).
// ---------------------------------------------------------------------------
__device__ __forceinline__ U8 loadA_f32(const float* Af, int kb, int K, bool rowok) {
  U8 u;
  if (rowok && kb + 8 <= K) {
    float4 f0 = *(const float4*)(Af + kb);
    float4 f1 = *(const float4*)(Af + kb + 4);
    u.b[0]=(__bf16)f0.x; u.b[1]=(__bf16)f0.y; u.b[2]=(__bf16)f0.z; u.b[3]=(__bf16)f0.w;
    u.b[4]=(__bf16)f1.x; u.b[5]=(__bf16)f1.y; u.b[6]=(__bf16)f1.z; u.b[7]=(__bf16)f1.w;
  } else {
#pragma unroll
    for (int j = 0; j < 8; ++j) {
      float f = (rowok && kb + j < K) ? Af[kb + j] : 0.f;
      u.b[j] = (__bf16)f;
    }
  }
  return u;
}

template<bool ABF16, bool CBF16, bool MISH, int NJ, int KPMAX>
__global__ __launch_bounds__(256) void gemm2(
    const void* __restrict__ Av, const unsigned short* __restrict__ Bt,
    const float* __restrict__ bias, void* __restrict__ Cv,
    int N, int M, int K, int lda, int ldc,
    long sA, long sB, long sC, float alpha, int Kpad)
{
  constexpr int BM = NJ * 16;
  __shared__ unsigned short Bs[BM * KPMAX];

  const int tid = threadIdx.x;
  const int col0 = blockIdx.x * BM, row0 = blockIdx.y * 64;

  // ---- stage B panel: contiguous uint4 copy, 4-deep ----
  {
    const unsigned short* Bp = Bt + (long)blockIdx.z * sB + (long)col0 * Kpad;
    int rows = M - col0; if (rows > BM) rows = BM;
    const int total = rows * Kpad;
    for (int i = tid * 8; i < total; i += TPB * 32) {
      uint4 a0, a1, a2, a3;
      bool b1 = i + TPB * 8  < total;
      bool b2 = i + TPB * 16 < total;
      bool b3 = i + TPB * 24 < total;
      a0 = *(const uint4*)&Bp[i];
      if (b1) a1 = *(const uint4*)&Bp[i + TPB * 8];
      if (b2) a2 = *(const uint4*)&Bp[i + TPB * 16];
      if (b3) a3 = *(const uint4*)&Bp[i + TPB * 24];
      *(uint4*)&Bs[i] = a0;
      if (b1) *(uint4*)&Bs[i + TPB * 8]  = a1;
      if (b2) *(uint4*)&Bs[i + TPB * 16] = a2;
      if (b3) *(uint4*)&Bs[i + TPB * 24] = a3;
    }
  }

  const int lane = tid & 63, w = tid >> 6;
  const int mrow = lane & 15, kg = lane >> 4;
  const int arow = row0 + w * 16 + mrow;
  const bool rowok = arow < N;

  const unsigned short* Ah = nullptr;
  const float* Af = nullptr;
  if (ABF16) Ah = (const unsigned short*)Av + (long)blockIdx.z * sA + (long)arow * lda;
  else       Af = (const float*)Av + (long)blockIdx.z * sA + (long)arow * lda;

  U8 ua;
  if (ABF16) ua.q = *(const uint4*)(Ah + kg * 8);
  else       ua   = loadA_f32(Af, kg * 8, K, rowok);

  __syncthreads();

  f32x4 acc[NJ];
#pragma unroll
  for (int j = 0; j < NJ; ++j) acc[j] = (f32x4)0.f;

  for (int k0 = 0; k0 < K; k0 += 32) {
    U8 un;
    bool more = (k0 + 32) < K;
    if (more) {
      if (ABF16) un.q = *(const uint4*)(Ah + k0 + 32 + kg * 8);
      else       un   = loadA_f32(Af, k0 + 32 + kg * 8, K, rowok);
    }
    const int kb = k0 + kg * 8;
#pragma unroll
    for (int j = 0; j < NJ; ++j) {
      U8 ub;
      ub.q = *(const uint4*)&Bs[(j * 16 + mrow) * Kpad + kb];
      acc[j] = __builtin_amdgcn_mfma_f32_16x16x32_bf16(ua.v, ub.v, acc[j], 0, 0, 0);
    }
    if (more) ua = un;
  }

  long cbase = (long)blockIdx.z * sC;
#pragma unroll
  for (int j = 0; j < NJ; ++j) {
    int gc = col0 + j * 16 + mrow;
    if (gc >= M) continue;
    float bb = bias ? bias[gc] : 0.f;
#pragma unroll
    for (int r = 0; r < 4; ++r) {
      int gr = row0 + w * 16 + kg * 4 + r;
      if (gr >= N) continue;
      float v = acc[j][r] * alpha + bb;
      if (MISH) v = mish_f(v);
      if (CBF16) ((unsigned short*)Cv)[cbase + (long)gr * ldc + gc] = f2bfu(v);
      else       ((float*)Cv)[cbase + (long)gr * ldc + gc] = v;
    }
  }
}

static inline int kpad_of(int K) { return ((K + 31) / 32) * 32 + 8; }

// ---------------------------------------------------------------------------
// prep: kind 0 = transpose-cast (K,M)->(M,Kpad); kind 1 = fp32 copy;
//       kind 2 = straight cast (M,K)->(M,Kpad) zero-padded.
// ---------------------------------------------------------------------------
struct PrepSeg { const float* src; void* dst; int K, M, Kpad, kind; };
struct PrepArgs { PrepSeg s[19]; };

__global__ __launch_bounds__(256) void prep_weights(PrepArgs a) {
  PrepSeg sg = a.s[blockIdx.x];
  if (sg.kind == 0) {
    unsigned short* d = (unsigned short*)sg.dst;
    int tot = sg.M * sg.Kpad;
    for (int i = threadIdx.x; i < tot; i += TPB) {
      int m = i / sg.Kpad, k = i - m * sg.Kpad;
      float f = (k < sg.K) ? sg.src[(long)k * sg.M + m] : 0.f;
      d[i] = f2bfu(f);
    }
  } else if (sg.kind == 1) {
    float* d = (float*)sg.dst;
    for (int i = threadIdx.x; i < sg.K; i += TPB) d[i] = sg.src[i];
  } else {
    unsigned short* d = (unsigned short*)sg.dst;
    int tot = sg.M * sg.Kpad;
    for (int i = threadIdx.x; i < tot; i += TPB) {
      int m = i / sg.Kpad, k = i - m * sg.Kpad;
      float f = (k < sg.K) ? sg.src[(long)m * sg.K + k] : 0.f;
      d[i] = f2bfu(f);
    }
  }
}

// bz[m] = sum_k b_in[k] * Wt[m][k] (+ bc[m]); Wt bf16 (M, ldw). grid*64 >= M.
__global__ __launch_bounds__(64) void bias_comb(const float* __restrict__ b_in,
                                                const unsigned short* __restrict__ Wt,
                                                int ldw, const float* __restrict__ bc,
                                                float* __restrict__ out, int M, int K)
{
  int m = blockIdx.x * 64 + threadIdx.x;
  if (m >= M) return;
  float s = bc ? bc[m] : 0.f;
  for (int k = 0; k < K; ++k) s += b_in[k] * bfu2f(Wt[(long)m * ldw + k]);
  out[m] = s;
}

// ---------------------------------------------------------------------------
// ktvt2 (R9-verified): Kt (R,72) slice; Vt (64,Rpad)=V^T via LDS tile.
// ---------------------------------------------------------------------------
__global__ __launch_bounds__(256) void ktvt2(
    const unsigned short* __restrict__ QKV, unsigned short* __restrict__ Kt,
    unsigned short* __restrict__ Vt, int R, int Rpad)
{
  __shared__ unsigned short tile[64][72];
  int g = blockIdx.x, tid = threadIdx.x;
  const unsigned short* q = QKV + (long)g * R * 192;
  unsigned short* kt = Kt + (long)g * R * 72;
  unsigned short* vt = Vt + (long)g * 64 * Rpad;

  {
    int c = tid & 63, w = tid >> 6;
    for (int r = w; r < R; r += 4)
      kt[r * 72 + c] = q[(long)r * 192 + 64 + c];
  }

  for (int r0 = 0; r0 < Rpad; r0 += 64) {
    __syncthreads();
    for (int i = tid; i < 64 * 64; i += TPB) {
      int rr = i >> 6, cc = i & 63;
      int r = r0 + rr;
      tile[cc][rr] = (r < R) ? q[(long)r * 192 + 128 + cc] : (unsigned short)0;
    }
    __syncthreads();
    int c = tid >> 2, j0 = (tid & 3) * 16;
    int lim = Rpad - r0; if (lim > 64) lim = 64;
    for (int jj = j0; jj < j0 + 16 && jj < lim; jj += 8) {
      uint4 qv = *(const uint4*)&tile[c][jj];
      *(uint4*)&vt[(long)c * Rpad + r0 + jj] = qv;
    }
  }
}

// ---------------------------------------------------------------------------
// adj_build (R8-verified): dense normalized adjacency per graph, bf16
// (R x Rpad), self-loop folded. A[d][s] = dinv[d]*dinv[s]*cnt + (s==d)*dinv^2.
// ---------------------------------------------------------------------------
__global__ __launch_bounds__(256) void adj_build(
    const int* __restrict__ src, const int* __restrict__ dst,
    unsigned short* __restrict__ Adj, int R, int Rpad, int EPG)
{
  __shared__ float dinv_s[256];
  __shared__ unsigned short ssrc[MAXEP];
  __shared__ int cnt[256];
  __shared__ int scan[256];
  __shared__ int offx[257];
  __shared__ int cur[256];
  __shared__ float rowbuf[4][256];

  int g = blockIdx.x, tid = threadIdx.x;
  long ebase = (long)g * EPG;
  int gR = g * R;

  cnt[tid] = 0;
  __syncthreads();
  for (int e = tid; e < EPG; e += TPB)
    atomicAdd(&cnt[dst[ebase + e] - gR], 1);
  __syncthreads();

  int x = cnt[tid];
  int pc = (x + 7) & ~7;
  scan[tid] = pc;
  __syncthreads();
#pragma unroll
  for (int s = 1; s < 256; s <<= 1) {
    int t = (tid >= s) ? scan[tid - s] : 0;
    __syncthreads();
    scan[tid] += t;
    __syncthreads();
  }
  if (tid == 0) offx[0] = 0;
  offx[tid + 1] = scan[tid];
  cur[tid] = scan[tid] - pc;
  dinv_s[tid] = rsqrtf((float)x + 1.f);
  {
    unsigned dummy2 = 0xFFFFFFFFu;
    for (int i = tid; i < MAXEP / 2; i += TPB) ((unsigned*)ssrc)[i] = dummy2;
  }
  __syncthreads();

  for (int e = tid; e < EPG; e += TPB) {
    int d = dst[ebase + e] - gR;
    int s = src[ebase + e] - gR;
    int pos = atomicAdd(&cur[d], 1);
    ssrc[pos] = (unsigned short)s;
  }
  __syncthreads();

  int lane = tid & 63, w = tid >> 6;
  float* rb = rowbuf[w];
  for (int d = w; d < R; d += 4) {
#pragma unroll
    for (int i = 0; i < 4; ++i) rb[lane + i * 64] = 0.f;
    int i0 = offx[d], i1 = offx[d + 1];
    for (int i = i0 + lane; i < i1; i += 64) {
      int s = ssrc[i];
      if (s < R) atomicAdd(&rb[s], dinv_s[s]);
    }
    float dd = dinv_s[d];
    int c0 = lane * 4;
    if (c0 < Rpad) {
      ushort4 o;
      float v0 = rb[c0]     + (c0     == d ? dd : 0.f);
      float v1 = rb[c0 + 1] + (c0 + 1 == d ? dd : 0.f);
      float v2 = rb[c0 + 2] + (c0 + 2 == d ? dd : 0.f);
      float v3 = rb[c0 + 3] + (c0 + 3 == d ? dd : 0.f);
      o.x = f2bfu(v0 * dd); o.y = f2bfu(v1 * dd);
      o.z = f2bfu(v2 * dd); o.w = f2bfu(v3 * dd);
      *(ushort4*)&Adj[((long)gR + d) * Rpad + c0] = o;
    }
  }
}

// transp64: per-graph (R x 64) bf16 -> (64 x Rpad) bf16, zero-padded cols>=R.
__global__ __launch_bounds__(256) void transp64(
    const unsigned short* __restrict__ X, unsigned short* __restrict__ XT,
    int R, int Rpad)
{
  __shared__ unsigned short tile[64][72];
  int g = blockIdx.x, tid = threadIdx.x;
  const unsigned short* xg = X + (long)g * R * 64;
  unsigned short* xt = XT + (long)g * 64 * Rpad;
  for (int r0 = 0; r0 < Rpad; r0 += 64) {
    __syncthreads();
    for (int i = tid; i < 64 * 64; i += TPB) {
      int rr = i >> 6, cc = i & 63;
      int r = r0 + rr;
      tile[cc][rr] = (r < R) ? xg[(long)r * 64 + cc] : (unsigned short)0;
    }
    __syncthreads();
    int c = tid >> 2, j0 = (tid & 3) * 16;
    int lim = Rpad - r0; if (lim > 64) lim = 64;
    for (int jj = j0; jj < j0 + 16 && jj < lim; jj += 8) {
      uint4 q = *(const uint4*)&tile[c][jj];
      *(uint4*)&xt[(long)c * Rpad + r0 + jj] = q;
    }
  }
}

// wave-per-row softmax in place on bf16; row length R <= 256
__global__ __launch_bounds__(256) void softmax_bf16(unsigned short* __restrict__ S,
                                                    int R, long rows)
{
  long wid = (long)blockIdx.x * 4 + (threadIdx.x >> 6);
  if (wid >= rows) return;
  int lane = threadIdx.x & 63;
  unsigned short* row = S + wid * R;
  float v[4];
  float mx = -1e30f;
#pragma unroll
  for (int t = 0; t < 4; ++t) {
    int j = lane + t * 64;
    v[t] = (j < R) ? bfu2f(row[j]) : -1e30f;
    mx = fmaxf(mx, v[t]);
  }
#pragma unroll
  for (int o = 32; o; o >>= 1) mx = fmaxf(mx, __shfl_xor(mx, o));
  float s = 0.f;
#pragma unroll
  for (int t = 0; t < 4; ++t) {
    int j = lane + t * 64;
    if (j < R) { v[t] = expf(v[t] - mx); s += v[t]; }
  }
#pragma unroll
  for (int o = 32; o; o >>= 1) s += __shfl_xor(s, o);
  float inv = 1.f / s;
#pragma unroll
  for (int t = 0; t < 4; ++t) {
    int j = lane + t * 64;
    if (j < R) row[j] = f2bfu(v[t] * inv);
  }
}

// out[idx] = inv * sum_g S[g*RR + idx]; 8-way unrolled
__global__ void meang_bf16(const unsigned short* __restrict__ S, float* __restrict__ out,
                           int RR, int G, float inv)
{
  int idx = blockIdx.x * TPB + threadIdx.x;
  if (idx >= RR) return;
  const unsigned short* p = S + idx;
  float s = 0.f;
  for (int g = 0; g + 8 <= G; g += 8) {
    s += bfu2f(p[(long)g * RR])       + bfu2f(p[(long)(g + 1) * RR]) +
         bfu2f(p[(long)(g + 2) * RR]) + bfu2f(p[(long)(g + 3) * RR]) +
         bfu2f(p[(long)(g + 4) * RR]) + bfu2f(p[(long)(g + 5) * RR]) +
         bfu2f(p[(long)(g + 6) * RR]) + bfu2f(p[(long)(g + 7) * RR]);
  }
  out[idx] = s * inv;
}

// per-graph mean over R rows (bf16 in). grid=G, 256 threads.
__global__ __launch_bounds__(256) void pool_mean_bf16(const unsigned short* __restrict__ X,
                                                      float* __restrict__ out, int R)
{
  __shared__ float part[4][64];
  int g = blockIdx.x, lane = threadIdx.x & 63, w = threadIdx.x >> 6;
  float s = 0.f;
  for (int r = w; r < R; r += 4)
    s += bfu2f(X[((long)g * R + r) * 64 + lane]);
  part[w][lane] = s;
  __syncthreads();
  if (w == 0)
    out[g * 64 + lane] = (part[0][lane] + part[1][lane] + part[2][lane] + part[3][lane]) * (1.f / R);
}

// per-graph mean over V gathered rows (bf16 in). grid=G, 64 threads.
__global__ __launch_bounds__(64) void sub_mean_kernel(const unsigned short* __restrict__ X,
                                                      const int* __restrict__ sub,
                                                      float* __restrict__ out, int V)
{
  int g = blockIdx.x, lane = threadIdx.x;
  float s = 0.f;
  for (int v = 0; v + 4 <= V; v += 4) {
    int i0 = sub[g * V + v],     i1 = sub[g * V + v + 1];
    int i2 = sub[g * V + v + 2], i3 = sub[g * V + v + 3];
    s += bfu2f(X[(long)i0 * 64 + lane]) + bfu2f(X[(long)i1 * 64 + lane]) +
         bfu2f(X[(long)i2 * 64 + lane]) + bfu2f(X[(long)i3 * 64 + lane]);
  }
  out[g * 64 + lane] = s * (1.f / V);
}

__global__ __launch_bounds__(64) void norm_rows_kernel(const float* __restrict__ X,
                                                       float* __restrict__ Y)
{
  int g = blockIdx.x, lane = threadIdx.x;
  float x = X[g * 64 + lane];
  float ss = x * x;
#pragma unroll
  for (int o = 32; o; o >>= 1) ss += __shfl_xor(ss, o);
  float n = fmaxf(sqrtf(ss), 1e-12f);
  Y[g * 64 + lane] = x / n;
}

__global__ __launch_bounds__(256) void closs_kernel(const float* __restrict__ An,
                                                    const float* __restrict__ Bn,
                                                    float* __restrict__ loss, int G,
                                                    float invTemp, float coef)
{
  int i = blockIdx.x;
  __shared__ float arow[64];
  __shared__ float logits[512];
  __shared__ float red[256];
  int t = threadIdx.x;
  if (t < 64) arow[t] = An[i * 64 + t];
  __syncthreads();
  for (int j = t; j < G; j += 256) {
    const float* bp = Bn + (long)j * 64;
    float d = 0.f;
#pragma unroll
    for (int k = 0; k < 64; ++k) d = fmaf(arow[k], bp[k], d);
    logits[j] = d * invTemp;
  }
  __syncthreads();
  float mx = -1e30f;
  for (int j = t; j < G; j += 256) mx = fmaxf(mx, logits[j]);
  red[t] = mx; __syncthreads();
  for (int o = 128; o; o >>= 1) { if (t < o) red[t] = fmaxf(red[t], red[t + o]); __syncthreads(); }
  mx = red[0]; __syncthreads();
  float s = 0.f;
  for (int j = t; j < G; j += 256) s += expf(logits[j] - mx);
  red[t] = s; __syncthreads();
  for (int o = 128; o; o >>= 1) { if (t < o) red[t] += red[t + o]; __syncthreads(); }
  if (t == 0) {
    float lse = mx + logf(red[0]);
    atomicAdd(loss, coef * (lse - logits[i]));
  }
}

__global__ __launch_bounds__(128) void head_kernel(
    const float* __restrict__ s1, const float* __restrict__ z1,
    const float* __restrict__ s2, const float* __restrict__ z2,
    const float* __restrict__ W1, const float* __restrict__ b1,
    const float* __restrict__ W2, const float* __restrict__ b2,
    float* __restrict__ out)
{
  int g = blockIdx.x, t = threadIdx.x;
  __shared__ float feat[256];
  __shared__ float hid[128];
  if (t < 64) {
    feat[t]       = s1[g * 64 + t];
    feat[64 + t]  = z1[g * 64 + t];
    feat[128 + t] = s2[g * 64 + t];
    feat[192 + t] = z2[g * 64 + t];
  }
  __syncthreads();
  float acc = b1[t];
  for (int k = 0; k < 256; ++k) acc = fmaf(feat[k], W1[k * 128 + t], acc);
  hid[t] = mish_f(acc);
  __syncthreads();
  if (t < 2) {
    float a2 = b2[t];
#pragma unroll
    for (int k = 0; k < 128; ++k) a2 = fmaf(hid[k], W2[k * 2 + t], a2);
    out[g * 2 + t] = a2;
  }
}

#define LAUNCH_GEMM(ABF,CBF,MISH,NJ,KP, A,B,BI,C, N,M,K,LDA,LDC,SA,SB,SC,BAT,AL,KPAD) \
  { dim3 g_(((M)+(NJ)*16-1)/((NJ)*16), ((N)+63)/64, (BAT)); \
    gemm2<ABF,CBF,MISH,NJ,KP><<<g_,256,0,stream>>>((A),(B),(BI),(C),(N),(M),(K),(LDA),(LDC),(SA),(SB),(SC),(AL),(KPAD)); }

extern "C" void kernel_launch(void* const* d_in, const int* in_sizes, int n_in,
                              void* d_out, int out_size, void* d_ws, size_t ws_size,
                              hipStream_t stream)
{
  const float* x1     = (const float*)d_in[0];
  const float* x2     = (const float*)d_in[1];
  const float* fcl_W  = (const float*)d_in[2];  const float* fcl_b  = (const float*)d_in[3];
  const float* fcr_W  = (const float*)d_in[4];  const float* fcr_b  = (const float*)d_in[5];
  const float* fcl1_W = (const float*)d_in[6];  const float* fcl1_b = (const float*)d_in[7];
  const float* fcr1_W = (const float*)d_in[8];  const float* fcr1_b = (const float*)d_in[9];
  const float* a1qW = (const float*)d_in[10]; const float* a1qb = (const float*)d_in[11];
  const float* a1kW = (const float*)d_in[12]; const float* a1kb = (const float*)d_in[13];
  const float* a1vW = (const float*)d_in[14]; const float* a1vb = (const float*)d_in[15];
  const float* a2qW = (const float*)d_in[16]; const float* a2qb = (const float*)d_in[17];
  const float* a2kW = (const float*)d_in[18]; const float* a2kb = (const float*)d_in[19];
  const float* a2vW = (const float*)d_in[20]; const float* a2vb = (const float*)d_in[21];
  const float* convW  = (const float*)d_in[22]; const float* convb  = (const float*)d_in[23];
  const float* conv1W = (const float*)d_in[24]; const float* conv1b = (const float*)d_in[25];
  const float* mlpW   = (const float*)d_in[26]; const float* mlpb   = (const float*)d_in[27];
  const float* fc1aW  = (const float*)d_in[28]; const float* fc1ab  = (const float*)d_in[29];
  const float* fc1bW  = (const float*)d_in[30]; const float* fc1bb  = (const float*)d_in[31];
  const int* ei1  = (const int*)d_in[32];
  const int* ei2  = (const int*)d_in[33];
  const int* sub1 = (const int*)d_in[36];
  const int* sub2 = (const int*)d_in[37];

  const int R1 = in_sizes[6] / 128;       // 200
  const int R2 = in_sizes[8] / 128;       // 160
  const int N1 = in_sizes[34];            // 102400
  const int N2 = in_sizes[35];            // 81920
  const int G  = N1 / R1;                 // 512
  const int E1 = in_sizes[32] / 2, E2 = in_sizes[33] / 2;
  const int EPG1 = E1 / G, EPG2 = E2 / G;
  const int V = in_sizes[36] / G;

  const int Kp1  = kpad_of(R1);           // 232
  const int Kp2  = kpad_of(R2);           // 168
  const int Kp1f = kpad_of(R1 + 3);       // 232
  const int Kp2f = kpad_of(R2 + 3);       // 200
  const int Rpad1 = Kp1, Rpad2 = Kp2;

  // ---------------- workspace layout ----------------
  char* wp = (char*)d_ws;
  auto alloc = [&](size_t bytes) -> char* {
    char* p = wp; wp += (bytes + 255) & ~(size_t)255; return p;
  };
  size_t raSh = (size_t)G * R1 * R1;
  if ((size_t)N1 * 128 > raSh) raSh = (size_t)N1 * 128;
  unsigned short* RA = (unsigned short*)alloc(raSh * 2);
  unsigned short* RB = (unsigned short*)alloc((size_t)N1 * 192 * 2);
  unsigned short* Kt = (unsigned short*)alloc((size_t)G * R1 * 72 * 2);
  unsigned short* Vt = (unsigned short*)alloc((size_t)G * 64 * Rpad1 * 2);  // also hW^T
  unsigned short* W5 = (unsigned short*)alloc((size_t)N1 * 64 * 2);         // PV out bf16
  unsigned short* Adj1 = (unsigned short*)alloc((size_t)G * R1 * Rpad1 * 2);
  unsigned short* Adj2 = (unsigned short*)alloc((size_t)G * R2 * Rpad2 * 2);
  // straight-cast originals (combine-GEMM B panels)
  unsigned short* fcl1n = (unsigned short*)alloc((size_t)R1 * 136 * 2);
  unsigned short* fcr1n = (unsigned short*)alloc((size_t)R2 * 136 * 2);
  unsigned short* fcln  = (unsigned short*)alloc((size_t)(R1 + 3) * 136 * 2);
  unsigned short* fcrn  = (unsigned short*)alloc((size_t)(R2 + 3) * 136 * 2);
  // QKV / conv weight transposed panels
  unsigned short* Wc1t   = (unsigned short*)alloc((size_t)192 * 136 * 2);
  unsigned short* Wc2t   = (unsigned short*)alloc((size_t)192 * 136 * 2);
  unsigned short* convt  = (unsigned short*)alloc((size_t)64 * 136 * 2);
  unsigned short* conv1t = (unsigned short*)alloc((size_t)64 * 72 * 2);
  unsigned short* mlpt   = (unsigned short*)alloc((size_t)64 * 72 * 2);
  // fused combined-weight panels (contiguous for single memset)
  size_t wzB1 = (size_t)192 * Kp1 * 2, wzB2 = (size_t)192 * Kp2 * 2;
  size_t wgB1 = (size_t)64 * Kp1f * 2, wgB2 = (size_t)64 * Kp2f * 2;
  char* comb = alloc(wzB1 + wzB2 + wgB1 + wgB2);
  unsigned short* Wz1t = (unsigned short*)comb;
  unsigned short* Wz2t = (unsigned short*)(comb + wzB1);
  unsigned short* Wg1t = (unsigned short*)(comb + wzB1 + wzB2);
  unsigned short* Wg2t = (unsigned short*)(comb + wzB1 + wzB2 + wgB1);
  float* bc1 = (float*)alloc(192 * 4);
  float* bc2 = (float*)alloc(192 * 4);
  float* bz1 = (float*)alloc(192 * 4);
  float* bz2 = (float*)alloc(192 * 4);
  float* bg1 = (float*)alloc(64 * 4);
  float* bg2 = (float*)alloc(64 * 4);
  float* Pz1 = (float*)alloc((size_t)G * 64 * 4);
  float* Pz2 = (float*)alloc((size_t)G * 64 * 4);
  float* Ps1 = (float*)alloc((size_t)G * 64 * 4);
  float* Ps2 = (float*)alloc((size_t)G * 64 * 4);
  float* Mt  = (float*)alloc((size_t)G * 64 * 4);
  float* n_s1 = (float*)alloc((size_t)G * 64 * 4);
  float* n_z2 = (float*)alloc((size_t)G * 64 * 4);
  float* n_z1 = (float*)alloc((size_t)G * 64 * 4);
  float* n_s2 = (float*)alloc((size_t)G * 64 * 4);
  (void)alloc(65536);   // tail slack for benign bf16-A row overreads

  float* loss = (float*)d_out;
  float* outp = loss + 1;
  float* aw1  = outp + (size_t)G * 2;
  float* aw2  = aw1 + (size_t)R1 * R1;

  hipMemsetAsync(d_out, 0, sizeof(float), stream);
  hipMemsetAsync(comb, 0, wzB1 + wzB2 + wgB1 + wgB2, stream);

  // ---------------- prep ----------------
  PrepArgs pa;
  int seg = 0;
  auto addp = [&](const float* s, unsigned short* d, int K, int M, int Kp, int kind) {
    pa.s[seg].src = s; pa.s[seg].dst = d; pa.s[seg].K = K; pa.s[seg].M = M;
    pa.s[seg].Kpad = Kp; pa.s[seg].kind = kind; seg++;
  };
  auto addb = [&](const float* s, float* d, int n) {
    pa.s[seg].src = s; pa.s[seg].dst = d; pa.s[seg].K = n; pa.s[seg].M = 0;
    pa.s[seg].Kpad = 0; pa.s[seg].kind = 1; seg++;
  };
  addp(fcl1_W, fcl1n, 128, R1, 136, 2);      // straight cast (R1,128)->(R1,136)
  addp(fcr1_W, fcr1n, 128, R2, 136, 2);
  addp(fcl_W,  fcln,  128, R1 + 3, 136, 2);
  addp(fcr_W,  fcrn,  128, R2 + 3, 136, 2);
  addp(a1qW, Wc1t,             128, 64, 136, 0);
  addp(a1kW, Wc1t + 64 * 136,  128, 64, 136, 0);
  addp(a1vW, Wc1t + 128 * 136, 128, 64, 136, 0);
  addp(a2qW, Wc2t,             128, 64, 136, 0);
  addp(a2kW, Wc2t + 64 * 136,  128, 64, 136, 0);
  addp(a2vW, Wc2t + 128 * 136, 128, 64, 136, 0);
  addp(convW,  convt,  128, 64, 136, 0);
  addp(conv1W, conv1t, 64, 64, 72, 0);
  addp(mlpW,   mlpt,   64, 64, 72, 0);
  addb(a1qb, bc1, 64); addb(a1kb, bc1 + 64, 64); addb(a1vb, bc1 + 128, 64);
  addb(a2qb, bc2, 64); addb(a2kb, bc2 + 64, 64); addb(a2vb, bc2 + 128, 64);
  prep_weights<<<seg, 256, 0, stream>>>(pa);

  // ---------------- combine weights: Wz = Wc^T @ W1^T, Wg = conv^T @ fcl^T --
  LAUNCH_GEMM(true, true, false, 8, 136, Wc1t, fcl1n, nullptr, Wz1t,
              192, R1, 128, 136, Kp1, 0, 0, 0, 1, 1.f, 136);
  LAUNCH_GEMM(true, true, false, 8, 136, Wc2t, fcr1n, nullptr, Wz2t,
              192, R2, 128, 136, Kp2, 0, 0, 0, 1, 1.f, 136);
  LAUNCH_GEMM(true, true, false, 8, 136, convt, fcln, nullptr, Wg1t,
              64, R1 + 3, 128, 136, Kp1f, 0, 0, 0, 1, 1.f, 136);
  LAUNCH_GEMM(true, true, false, 8, 136, convt, fcrn, nullptr, Wg2t,
              64, R2 + 3, 128, 136, Kp2f, 0, 0, 0, 1, 1.f, 136);
  bias_comb<<<3, 64, 0, stream>>>(fcl1_b, Wc1t, 136, bc1, bz1, 192, 128);
  bias_comb<<<3, 64, 0, stream>>>(fcr1_b, Wc2t, 136, bc2, bz2, 192, 128);
  bias_comb<<<1, 64, 0, stream>>>(fcl_b, convt, 136, nullptr, bg1, 64, 128);
  bias_comb<<<1, 64, 0, stream>>>(fcr_b, convt, 136, nullptr, bg2, 64, 128);

  // ======== attention branch, side 1: QKV directly from x1 ========
  LAUNCH_GEMM(false, true, false, 6, 232, x1, Wz1t, bz1, RB,
              N1, 192, R1, R1 + 3, 192, 0, 0, 0, 1, 1.f, Kp1);
  ktvt2<<<G, 256, 0, stream>>>(RB, Kt, Vt, R1, Rpad1);
  LAUNCH_GEMM(true, true, false, 8, 72, RB, Kt, nullptr, RA,
              R1, R1, 64, 192, R1, (long)R1 * 192, (long)R1 * 72, (long)R1 * R1,
              G, 0.125f, 72);
  {
    long rows = (long)G * R1;
    softmax_bf16<<<(int)((rows + 3) / 4), 256, 0, stream>>>(RA, R1, rows);
    meang_bf16<<<(R1 * R1 + TPB - 1) / TPB, TPB, 0, stream>>>(RA, aw1, R1 * R1, G, 1.f / G);
  }
  LAUNCH_GEMM(true, true, false, 4, 232, RA, Vt, nullptr, W5,
              R1, 64, R1, R1, 64, (long)R1 * R1, (long)64 * Rpad1, (long)R1 * 64,
              G, 1.f, Rpad1);
  pool_mean_bf16<<<G, 256, 0, stream>>>(W5, Pz1, R1);

  // ======== attention branch, side 2 ========
  LAUNCH_GEMM(false, true, false, 6, 232, x2, Wz2t, bz2, RB,
              N2, 192, R2, R2 + 3, 192, 0, 0, 0, 1, 1.f, Kp2);
  ktvt2<<<G, 256, 0, stream>>>(RB, Kt, Vt, R2, Rpad2);
  LAUNCH_GEMM(true, true, false, 8, 72, RB, Kt, nullptr, RA,
              R2, R2, 64, 192, R2, (long)R2 * 192, (long)R2 * 72, (long)R2 * R2,
              G, 0.125f, 72);
  {
    long rows = (long)G * R2;
    softmax_bf16<<<(int)((rows + 3) / 4), 256, 0, stream>>>(RA, R2, rows);
    meang_bf16<<<(R2 * R2 + TPB - 1) / TPB, TPB, 0, stream>>>(RA, aw2, R2 * R2, G, 1.f / G);
  }
  LAUNCH_GEMM(true, true, false, 4, 232, RA, Vt, nullptr, W5,
              R2, 64, R2, R2, 64, (long)R2 * R2, (long)64 * Rpad2, (long)R2 * 64,
              G, 1.f, Rpad2);
  pool_mean_bf16<<<G, 256, 0, stream>>>(W5, Pz2, R2);

  // ======== GCN branch, side 1: hW0 directly from x1 ========
  unsigned short* hW0 = RB;
  unsigned short* hW1 = RB + (size_t)N1 * 64;
  unsigned short* hW2 = RB + (size_t)N1 * 128;
  LAUNCH_GEMM(false, true, false, 4, 232, x1, Wg1t, bg1, hW0,
              N1, 64, R1 + 3, R1 + 3, 64, 0, 0, 0, 1, 1.f, Kp1f);
  adj_build<<<G, 256, 0, stream>>>(ei1, ei1 + E1, Adj1, R1, Rpad1, EPG1);
  transp64<<<G, 256, 0, stream>>>(hW0, Vt, R1, Rpad1);
  LAUNCH_GEMM(true, true, true, 4, 232, Adj1, Vt, convb, hW1,
              R1, 64, R1, Rpad1, 64, (long)R1 * Rpad1, (long)64 * Rpad1, (long)R1 * 64,
              G, 1.f, Rpad1);
  LAUNCH_GEMM(true, true, false, 4, 136, hW1, conv1t, nullptr, hW2,
              N1, 64, 64, 64, 64, 0, 0, 0, 1, 1.f, 72);
  transp64<<<G, 256, 0, stream>>>(hW2, Vt, R1, Rpad1);
  LAUNCH_GEMM(true, true, false, 4, 232, Adj1, Vt, conv1b, hW0,
              R1, 64, R1, Rpad1, 64, (long)R1 * Rpad1, (long)64 * Rpad1, (long)R1 * 64,
              G, 1.f, Rpad1);
  sub_mean_kernel<<<G, 64, 0, stream>>>(hW0, sub1, Mt, V);
  LAUNCH_GEMM(false, false, false, 4, 136, Mt, mlpt, mlpb, Ps1,
              G, 64, 64, 64, 64, 0, 0, 0, 1, 1.f, 72);

  // ======== GCN branch, side 2 ========
  LAUNCH_GEMM(false, true, false, 4, 232, x2, Wg2t, bg2, hW0,
              N2, 64, R2 + 3, R2 + 3, 64, 0, 0, 0, 1, 1.f, Kp2f);
  adj_build<<<G, 256, 0, stream>>>(ei2, ei2 + E2, Adj2, R2, Rpad2, EPG2);
  transp64<<<G, 256, 0, stream>>>(hW0, Vt, R2, Rpad2);
  LAUNCH_GEMM(true, true, true, 4, 232, Adj2, Vt, convb, hW1,
              R2, 64, R2, Rpad2, 64, (long)R2 * Rpad2, (long)64 * Rpad2, (long)R2 * 64,
              G, 1.f, Rpad2);
  LAUNCH_GEMM(true, true, false, 4, 136, hW1, conv1t, nullptr, hW2,
              N2, 64, 64, 64, 64, 0, 0, 0, 1, 1.f, 72);
  transp64<<<G, 256, 0, stream>>>(hW2, Vt, R2, Rpad2);
  LAUNCH_GEMM(true, true, false, 4, 232, Adj2, Vt, conv1b, hW0,
              R2, 64, R2, Rpad2, 64, (long)R2 * Rpad2, (long)64 * Rpad2, (long)R2 * 64,
              G, 1.f, Rpad2);
  sub_mean_kernel<<<G, 64, 0, stream>>>(hW0, sub2, Mt, V);
  LAUNCH_GEMM(false, false, false, 4, 136, Mt, mlpt, mlpb, Ps2,
              G, 64, 64, 64, 64, 0, 0, 0, 1, 1.f, 72);

  // ======== contrastive loss + head ========
  norm_rows_kernel<<<G, 64, 0, stream>>>(Ps1, n_s1);
  norm_rows_kernel<<<G, 64, 0, stream>>>(Pz2, n_z2);
  norm_rows_kernel<<<G, 64, 0, stream>>>(Pz1, n_z1);
  norm_rows_kernel<<<G, 64, 0, stream>>>(Ps2, n_s2);
  const float invTemp = 1.f / 0.6f;
  closs_kernel<<<G, 256, 0, stream>>>(n_s1, n_z2, loss, G, invTemp, 1.f / G);
  closs_kernel<<<G, 256, 0, stream>>>(n_z1, n_s2, loss, G, invTemp, 1.f / G);

  head_kernel<<<G, 128, 0, stream>>>(Ps1, Pz1, Ps2, Pz2, fc1aW, fc1ab, fc1bW, fc1bb, outp);
}